// Round 16
// baseline (206.861 us; speedup 1.0000x reference)
//
#include <hip/hip_runtime.h>
#include <hip/hip_bf16.h>

#define DEV __device__ __forceinline__

typedef __attribute__((ext_vector_type(8))) short bf16x8;
typedef __attribute__((ext_vector_type(4))) float f32x4;
typedef __attribute__((ext_vector_type(16))) float f32x16;

// ---------- helpers ----------
DEV short f2bf(float x){ __hip_bfloat16 h = __float2bfloat16(x); return *(short*)&h; }
DEV unsigned pack2bf(float a, float b){
  return (unsigned)(unsigned short)f2bf(a) | ((unsigned)(unsigned short)f2bf(b) << 16);
}
DEV float gelu_fast(float x){
  float z = 0.7978845608028654f*(x + 0.044715f*x*x*x);
  float e = __expf(-2.f*z);
  return x / (1.f + e);
}

#define SB 4096
#define NT 16384
#define DM 64

// ---------- weight convert+transpose: f32 [K][N] -> bf16 [N][K], 32x32 tiles ----------
__global__ __launch_bounds__(256) void wconv(
    const float* __restrict__ wq, const float* __restrict__ wk,
    const float* __restrict__ wv, const float* __restrict__ wo,
    const float* __restrict__ w1, const float* __restrict__ w2,
    short* __restrict__ wqT, short* __restrict__ wkT,
    short* __restrict__ wvT, short* __restrict__ woT,
    short* __restrict__ w1T, short* __restrict__ w2T)
{
  int t = blockIdx.x, l = blockIdx.y;
  const float* src; short* dst; int K, N, kt, nt;
  if (t < 16) {
    int m = t >> 2, sub = t & 3; kt = sub >> 1; nt = sub & 1; K = 64; N = 64;
    const float* s4[4] = {wq, wk, wv, wo};
    short*       d4[4] = {wqT, wkT, wvT, woT};
    src = s4[m] + l*4096; dst = d4[m] + l*4096;
  } else if (t < 48) {
    kt = (t-16) >> 4; nt = (t-16) & 15; K = 64; N = 512;
    src = w1 + l*32768; dst = w1T + l*32768;
  } else {
    kt = (t-48) >> 1; nt = (t-48) & 1; K = 512; N = 64;
    src = w2 + l*32768; dst = w2T + l*32768;
  }
  __shared__ float lds[32][33];
  int tx = threadIdx.x & 31, ty = threadIdx.x >> 5;
  int k0 = kt*32, n0 = nt*32;
  #pragma unroll
  for (int j=0;j<4;++j) lds[ty+8*j][tx] = src[(size_t)(k0+ty+8*j)*N + n0 + tx];
  __syncthreads();
  #pragma unroll
  for (int j=0;j<4;++j) {
    int nn = ty+8*j;
    dst[(size_t)(n0+nn)*K + k0 + tx] = f2bf(lds[tx][nn]);
  }
}

// ---------- building blocks ----------
DEV void make_frags_ln(const float* rowp, float mean, float inv,
    const float* __restrict__ s, const float* __restrict__ b, int kq,
    bf16x8& a0, bf16x8& a1){
  #pragma unroll
  for (int i=0;i<8;++i) a0[i] = f2bf((rowp[kq*8+i]-mean)*inv*s[kq*8+i]+b[kq*8+i]);
  #pragma unroll
  for (int i=0;i<8;++i) a1[i] = f2bf((rowp[32+kq*8+i]-mean)*inv*s[32+kq*8+i]+b[32+kq*8+i]);
}

// ---------- head: embed + posemb + LN1(0) + qkv(0); 32 rows, grid 512 ----------
__global__ __launch_bounds__(256,4) void embed_head(
    const int* __restrict__ x, const float* __restrict__ emb,
    const float* __restrict__ lns, const float* __restrict__ lnb,
    const short* __restrict__ wqT, const short* __restrict__ wkT, const short* __restrict__ wvT,
    const float* __restrict__ bq, const float* __restrict__ bk, const float* __restrict__ bv,
    unsigned short* __restrict__ qo, unsigned short* __restrict__ ko, unsigned short* __restrict__ vo,
    float* __restrict__ h)
{
  __shared__ float hN[32][76];
  __shared__ float mu[32], iv[32];

  const int bid = blockIdx.x;
  const int row_g0 = bid * 32;
  const int tid = threadIdx.x;
  const int w = tid >> 6, lane = tid & 63;
  const int r = lane & 15, kq = lane >> 4;
  const int wr0 = (w >> 1) * 16;
  const int cc0 = (w & 1) * 32;
  const int srow = tid >> 3, sdq = tid & 7;

  // qkv weight prefetch
  bf16x8 qwb[12];
  #pragma unroll
  for (int m=0;m<3;++m){
    const short* WT = m==0?wqT:(m==1?wkT:wvT);
    const short* qp0 = WT + (size_t)(cc0 + r)*64 + kq*8;
    const short* qp1 = WT + (size_t)(cc0 + 16 + r)*64 + kq*8;
    qwb[4*m+0] = *(const bf16x8*)(qp0);
    qwb[4*m+1] = *(const bf16x8*)(qp0 + 32);
    qwb[4*m+2] = *(const bf16x8*)(qp1);
    qwb[4*m+3] = *(const bf16x8*)(qp1 + 32);
  }

  {
    int tg = row_g0 + srow;
    int s = tg & (SB-1);
    int tok = x[tg];
    #pragma unroll
    for (int i=0;i<8;++i) {
      int d = sdq*8 + i;
      float fe = (float)(d & ~1) * (1.0f/64.0f);
      float invk = __expf(-9.210340371976184f * fe);
      float ang = (float)s * invk;
      float pe = (d & 1) ? __cosf(ang) : __sinf(ang);
      float val = emb[tok*DM + d] + pe;
      hN[srow][d] = val;
      h[(size_t)tg*DM + d] = val;
    }
  }
  __syncthreads();

  // LN stats
  {
    const float* p = &hN[srow][sdq*8];
    float v[8];
    float sum = 0.f;
    #pragma unroll
    for (int i=0;i<8;++i){ v[i] = p[i]; sum += v[i]; }
    sum += __shfl_xor(sum, 1, 64); sum += __shfl_xor(sum, 2, 64); sum += __shfl_xor(sum, 4, 64);
    float mean = sum * (1.f/64.f);
    float sq = 0.f;
    #pragma unroll
    for (int i=0;i<8;++i){ float d = v[i]-mean; sq += d*d; }
    sq += __shfl_xor(sq, 1, 64); sq += __shfl_xor(sq, 2, 64); sq += __shfl_xor(sq, 4, 64);
    if (sdq == 0) { mu[srow] = mean; iv[srow] = rsqrtf(sq*(1.f/64.f) + 1e-6f); }
  }
  __syncthreads();

  // qkv
  const float qscale = 0.35355339059327373f;
  bf16x8 a0, a1;
  make_frags_ln(&hN[wr0+r][0], mu[wr0+r], iv[wr0+r], lns, lnb, kq, a0, a1);
  f32x4 aq[2] = {(f32x4){0,0,0,0},(f32x4){0,0,0,0}};
  f32x4 akk[2] = {(f32x4){0,0,0,0},(f32x4){0,0,0,0}};
  f32x4 av[2] = {(f32x4){0,0,0,0},(f32x4){0,0,0,0}};
  #pragma unroll
  for (int ct=0; ct<2; ++ct) {
    aq[ct]  = __builtin_amdgcn_mfma_f32_16x16x32_bf16(a0, qwb[0+2*ct],  aq[ct], 0, 0, 0);
    aq[ct]  = __builtin_amdgcn_mfma_f32_16x16x32_bf16(a1, qwb[1+2*ct],  aq[ct], 0, 0, 0);
    akk[ct] = __builtin_amdgcn_mfma_f32_16x16x32_bf16(a0, qwb[4+2*ct],  akk[ct], 0, 0, 0);
    akk[ct] = __builtin_amdgcn_mfma_f32_16x16x32_bf16(a1, qwb[5+2*ct],  akk[ct], 0, 0, 0);
    av[ct]  = __builtin_amdgcn_mfma_f32_16x16x32_bf16(a0, qwb[8+2*ct],  av[ct], 0, 0, 0);
    av[ct]  = __builtin_amdgcn_mfma_f32_16x16x32_bf16(a1, qwb[9+2*ct],  av[ct], 0, 0, 0);
  }
  #pragma unroll
  for (int ct=0; ct<2; ++ct) {
    int col = cc0 + ct*16 + r;
    float bqv = bq[col], bkv = bk[col], bvv = bv[col];
    #pragma unroll
    for (int j=0;j<4;++j) {
      size_t oi = (size_t)(row_g0 + wr0 + kq*4 + j)*DM + col;
      qo[oi] = (unsigned short)f2bf((aq[ct][j] + bqv)*qscale);
      ko[oi] = (unsigned short)f2bf(akk[ct][j] + bkv);
      vo[oi] = (unsigned short)f2bf(av[ct][j] + bvv);
    }
  }
}

// ---------- merged layer kernel: attention + attnout + FFN + next-qkv ----------
template<bool LAST>
__global__ __launch_bounds__(512,2) void layer_kernel(
    const unsigned short* __restrict__ qin, const unsigned short* __restrict__ kin,
    const unsigned short* __restrict__ vin,
    const short* __restrict__ woT, const float* __restrict__ bo,
    const float* __restrict__ ln2s, const float* __restrict__ ln2b,
    const short* __restrict__ w1T, const float* __restrict__ b1,
    const short* __restrict__ w2T, const float* __restrict__ b2,
    const float* __restrict__ lns, const float* __restrict__ lnb,   // LN1(next) or LNf
    const short* __restrict__ wqT, const short* __restrict__ wkT, const short* __restrict__ wvT,
    const float* __restrict__ bq, const float* __restrict__ bk, const float* __restrict__ bv,
    unsigned short* __restrict__ qo, unsigned short* __restrict__ ko, unsigned short* __restrict__ vo,
    float* __restrict__ h, float* __restrict__ part,
    const float* __restrict__ wcls, const float* __restrict__ bcls,
    float* __restrict__ out, unsigned* __restrict__ cnt)
{
  __shared__ uint4 regA4[4608];   // 73728 B: Ks | (abL + hN + facc)
  __shared__ uint4 regB4[4672];   // 74752 B: Vs | mid
  __shared__ float mu[64], iv[64];
  __shared__ int lastflag;

  unsigned short* Ks  = (unsigned short*)regA4;              // [576][64], swizzled
  unsigned short* abL = (unsigned short*)regA4;              // [64][72] bf16 (post-attn)
  float (*hN)[68]   = (float(*)[68])((char*)regA4 + 9216);
  float (*facc)[68] = (float(*)[68])((char*)regA4 + 26624);
  unsigned short* Vs = (unsigned short*)regB4;               // [64][584] transposed
  short (*mid)[520]  = (short(*)[520])regB4;

  const int bid = blockIdx.x;
  const int row_g0 = bid * 64;
  const int tid = threadIdx.x;
  const int w = tid >> 6, lane = tid & 63;
  const int r = lane & 15, kq = lane >> 4;
  const int srow = tid >> 3, sd8 = tid & 7;

  const int bbase = row_g0 & ~(SB-1);     // batch base token index
  const int kwin0 = row_g0 - 256;         // global token index of staged key 0

  // ---- stage K [576][64] (swizzled; grp-major: writes conflict-free) ----
  for (int idx = tid; idx < 4608; idx += 512) {
    int e = idx >> 3, grp = idx & 7;
    int g = kwin0 + e;
    uint4 kv = make_uint4(0,0,0,0);
    if ((unsigned)(g - bbase) < (unsigned)SB)
      kv = *(const uint4*)(kin + (size_t)g*DM + grp*8);
    *(uint4*)(Ks + e*64 + ((grp ^ (e & 7)) << 3)) = kv;
  }
  // ---- stage V^T [64][584] (e-major: scatter writes 2-way only) ----
  for (int idx = tid; idx < 4608; idx += 512) {
    int grp = idx / 576, e = idx - grp*576;
    int g = kwin0 + e;
    uint4 vv = make_uint4(0,0,0,0);
    if ((unsigned)(g - bbase) < (unsigned)SB)
      vv = *(const uint4*)(vin + (size_t)g*DM + grp*8);
    const unsigned short* pv = (const unsigned short*)&vv;
    #pragma unroll
    for (int d = 0; d < 8; ++d) Vs[(grp*8 + d)*584 + e] = pv[d];
  }
  __syncthreads();

  // ---- attention: wave w = head w; q-subtiles qs=0,1 ----
  {
    const int qc = lane & 31;
    const int hf = lane >> 5;

    auto attn_job = [&](int qs, f32x16& oacc, float& lacc) {
      const int qglob = row_g0 + qs*32 + qc;
      bf16x8 qfrag = {};
      if (hf == 0) qfrag = *(const bf16x8*)(qin + (size_t)qglob*DM + w*8);
      for (int t = 0; t <= 16; ++t) {
        const int k0l = qs*32 + 32*t;
        const int k0g = kwin0 + k0l;
        if (k0g > bbase + SB-1 || k0g + 31 < bbase) continue;

        bf16x8 kfrag = {};
        if (hf == 0) {
          int e = k0l + qc;
          kfrag = *(const bf16x8*)(Ks + e*64 + ((w ^ (e & 7)) << 3));
        }
        f32x16 s = __builtin_amdgcn_mfma_f32_32x32x16_bf16(kfrag, qfrag, (f32x16){}, 0, 0, 0);

        float pp[16];
        bool needmask = (t == 0) | (t == 16) | (k0g < bbase) | (k0g + 31 > bbase + SB-1);
        if (needmask) {
          #pragma unroll
          for (int rr = 0; rr < 16; ++rr) {
            int klg = k0g + (rr&3) + 8*(rr>>2) + 4*hf;
            bool ok = ((unsigned)(klg - qglob + 256) <= 512u) &&
                      ((unsigned)(klg - bbase) < (unsigned)SB);
            pp[rr] = ok ? __expf(s[rr]) : 0.f;
          }
        } else {
          #pragma unroll
          for (int rr = 0; rr < 16; ++rr) pp[rr] = __expf(s[rr]);
        }
        #pragma unroll
        for (int rr = 0; rr < 16; ++rr) lacc += pp[rr];

        unsigned pk[8];
        #pragma unroll
        for (int j = 0; j < 8; ++j) pk[j] = pack2bf(pp[2*j], pp[2*j+1]);
        unsigned sw[8];
        #pragma unroll
        for (int j = 0; j < 8; ++j) sw[j] = __shfl_xor(pk[j], 32, 64);

        union { unsigned u[4]; bf16x8 v; } pbA;
        pbA.u[0] = hf ? sw[2] : pk[0];
        pbA.u[1] = hf ? sw[3] : pk[1];
        pbA.u[2] = hf ? pk[2] : sw[0];
        pbA.u[3] = hf ? pk[3] : sw[1];
        bf16x8 va1 = {};
        if (qc < 8) va1 = *(const bf16x8*)(Vs + (w*8 + qc)*584 + k0l + 8*hf);
        oacc = __builtin_amdgcn_mfma_f32_32x32x16_bf16(va1, pbA.v, oacc, 0, 0, 0);

        union { unsigned u[4]; bf16x8 v; } pbB;
        pbB.u[0] = hf ? sw[6] : pk[4];
        pbB.u[1] = hf ? sw[7] : pk[5];
        pbB.u[2] = hf ? pk[6] : sw[4];
        pbB.u[3] = hf ? pk[7] : sw[5];
        bf16x8 va2 = {};
        if (qc < 8) va2 = *(const bf16x8*)(Vs + (w*8 + qc)*584 + k0l + 16 + 8*hf);
        oacc = __builtin_amdgcn_mfma_f32_32x32x16_bf16(va2, pbB.v, oacc, 0, 0, 0);
      }
    };

    f32x16 oacc0 = {}; float la0 = 0.f;
    f32x16 oacc1 = {}; float la1 = 0.f;
    attn_job(0, oacc0, la0);
    attn_job(1, oacc1, la1);
    float rcp0 = 1.f / (la0 + __shfl_xor(la0, 32, 64));
    float rcp1 = 1.f / (la1 + __shfl_xor(la1, 32, 64));
    __syncthreads();    // all Ks/Vs reads complete

    unsigned short ov[4];
    #pragma unroll
    for (int j = 0; j < 4; ++j) ov[j] = (unsigned short)f2bf(oacc0[j] * rcp0);
    *(uint2*)(abL + (qc)*72 + w*8 + 4*hf) = *(uint2*)ov;
    #pragma unroll
    for (int j = 0; j < 4; ++j) ov[j] = (unsigned short)f2bf(oacc1[j] * rcp1);
    *(uint2*)(abL + (32 + qc)*72 + w*8 + 4*hf) = *(uint2*)ov;
  }
  __syncthreads();

  // ---- attn-out projection + residual: wave (rh,ct) = 32 rows x 16 cols ----
  {
    const int rh = w >> 2, ct = w & 3;
    const int col = ct*16 + r;
    const short* wp = woT + (size_t)col*64 + kq*8;
    bf16x8 wb0 = *(const bf16x8*)(wp);
    bf16x8 wb1 = *(const bf16x8*)(wp + 32);
    #pragma unroll
    for (int rf=0; rf<2; ++rf) {
      const short* abp = (const short*)(abL + (rh*32 + rf*16 + r)*72 + kq*8);
      bf16x8 a0 = *(const bf16x8*)abp;
      bf16x8 a1 = *(const bf16x8*)(abp + 32);
      f32x4 acc = (f32x4){0.f,0.f,0.f,0.f};
      acc = __builtin_amdgcn_mfma_f32_16x16x32_bf16(a0, wb0, acc, 0, 0, 0);
      acc = __builtin_amdgcn_mfma_f32_16x16x32_bf16(a1, wb1, acc, 0, 0, 0);
      #pragma unroll
      for (int j=0;j<4;++j) {
        int rl = rh*32 + rf*16 + kq*4 + j;
        hN[rl][col] = acc[j] + bo[col] + h[(size_t)(row_g0+rl)*DM + col];
      }
    }
  }
  __syncthreads();

  // LN2 stats
  {
    const float* p = &hN[srow][sd8*8];
    float v[8];
    float sum = 0.f;
    #pragma unroll
    for (int i=0;i<8;++i){ v[i] = p[i]; sum += v[i]; }
    sum += __shfl_xor(sum, 1, 64); sum += __shfl_xor(sum, 2, 64); sum += __shfl_xor(sum, 4, 64);
    float mean = sum * (1.f/64.f);
    float sq = 0.f;
    #pragma unroll
    for (int i=0;i<8;++i){ float d = v[i]-mean; sq += d*d; }
    sq += __shfl_xor(sq, 1, 64); sq += __shfl_xor(sq, 2, 64); sq += __shfl_xor(sq, 4, 64);
    if (sd8 == 0) { mu[srow] = mean; iv[srow] = rsqrtf(sq*(1.f/64.f) + 1e-6f); }
  }
  __syncthreads();

  // ---- fc1: wave w -> cols [64w, 64w+64), all 64 rows ----
  {
    bf16x8 a[4][2];
    #pragma unroll
    for (int rf=0; rf<4; ++rf)
      make_frags_ln(&hN[rf*16 + r][0], mu[rf*16 + r], iv[rf*16 + r], ln2s, ln2b, kq, a[rf][0], a[rf][1]);
    const int gc0 = w*64;
    bf16x8 wb[4][2];
    #pragma unroll
    for (int ct=0; ct<4; ++ct) {
      const short* wp = w1T + (size_t)(gc0 + ct*16 + r)*64 + kq*8;
      wb[ct][0] = *(const bf16x8*)(wp);
      wb[ct][1] = *(const bf16x8*)(wp + 32);
    }
    f32x4 acc1[4][4];
    #pragma unroll
    for (int ct=0;ct<4;++ct)
      #pragma unroll
      for (int rf=0;rf<4;++rf) acc1[ct][rf] = (f32x4){0.f,0.f,0.f,0.f};
    #pragma unroll
    for (int ct=0; ct<4; ++ct)
      #pragma unroll
      for (int rf=0; rf<4; ++rf) {
        acc1[ct][rf] = __builtin_amdgcn_mfma_f32_16x16x32_bf16(a[rf][0], wb[ct][0], acc1[ct][rf], 0, 0, 0);
        acc1[ct][rf] = __builtin_amdgcn_mfma_f32_16x16x32_bf16(a[rf][1], wb[ct][1], acc1[ct][rf], 0, 0, 0);
      }
    __syncthreads();   // Vs region free before mid writes
    #pragma unroll
    for (int ct=0; ct<4; ++ct) {
      int gcol = gc0 + ct*16 + r;
      float bb = b1[gcol];
      #pragma unroll
      for (int rf=0; rf<4; ++rf)
        #pragma unroll
        for (int j=0; j<4; ++j)
          mid[rf*16 + kq*4 + j][gcol] = f2bf(gelu_fast(acc1[ct][rf][j] + bb));
    }
  }
  __syncthreads();

  // ---- fc2: wave (kh = w>>2 K-half, ct2 = w&3 coltile): all 64 rows ----
  {
    const int kh = w >> 2, ct2 = w & 3;
    const int col2 = ct2*16 + r;
    bf16x8 wf[8];
    #pragma unroll
    for (int ks=0; ks<8; ++ks)
      wf[ks] = *(const bf16x8*)(w2T + (size_t)col2*512 + kh*256 + ks*32 + kq*8);
    f32x4 acc2[4];
    #pragma unroll
    for (int rf=0;rf<4;++rf) acc2[rf] = (f32x4){0.f,0.f,0.f,0.f};
    #pragma unroll
    for (int ks=0; ks<8; ++ks)
      #pragma unroll
      for (int rf=0; rf<4; ++rf) {
        bf16x8 af = *(const bf16x8*)(&mid[rf*16 + r][kh*256 + ks*32 + kq*8]);
        acc2[rf] = __builtin_amdgcn_mfma_f32_16x16x32_bf16(af, wf[ks], acc2[rf], 0, 0, 0);
      }
    if (kh == 0) {
      #pragma unroll
      for (int rf=0; rf<4; ++rf)
        #pragma unroll
        for (int j=0;j<4;++j)
          facc[rf*16 + kq*4 + j][col2] = acc2[rf][j];
    }
    __syncthreads();
    if (kh == 1) {
      float bb = b2[col2];
      #pragma unroll
      for (int rf=0; rf<4; ++rf)
        #pragma unroll
        for (int j=0;j<4;++j) {
          int rl = rf*16 + kq*4 + j;
          float val = acc2[rf][j] + facc[rl][col2] + bb + hN[rl][col2];
          hN[rl][col2] = val;
          h[(size_t)(row_g0+rl)*DM + col2] = val;
        }
    }
  }
  __syncthreads();

  // LN stats for LN1(next) / LNf
  {
    const float* p = &hN[srow][sd8*8];
    float v[8];
    float sum = 0.f;
    #pragma unroll
    for (int i=0;i<8;++i){ v[i] = p[i]; sum += v[i]; }
    sum += __shfl_xor(sum, 1, 64); sum += __shfl_xor(sum, 2, 64); sum += __shfl_xor(sum, 4, 64);
    float mean = sum * (1.f/64.f);
    float sq = 0.f;
    #pragma unroll
    for (int i=0;i<8;++i){ float d = v[i]-mean; sq += d*d; }
    sq += __shfl_xor(sq, 1, 64); sq += __shfl_xor(sq, 2, 64); sq += __shfl_xor(sq, 4, 64);
    if (sd8 == 0) { mu[srow] = mean; iv[srow] = rsqrtf(sq*(1.f/64.f) + 1e-6f); }
  }
  __syncthreads();

  if constexpr (!LAST) {
    // qkv of (next) layer: 12 jobs; wave w does jobs {w, w+8}
    const float qscale = 0.35355339059327373f;
    bf16x8 a[4][2];
    #pragma unroll
    for (int rf=0; rf<4; ++rf)
      make_frags_ln(&hN[rf*16 + r][0], mu[rf*16 + r], iv[rf*16 + r], lns, lnb, kq, a[rf][0], a[rf][1]);
    #pragma unroll
    for (int rep=0; rep<2; ++rep) {
      int jj = w + rep*8;
      if (jj < 12) {
        int m = jj >> 2, ct = jj & 3;
        const short* WT = m==0 ? wqT : (m==1 ? wkT : wvT);
        int col = ct*16 + r;
        const short* wp = WT + (size_t)col*64 + kq*8;
        bf16x8 wb0 = *(const bf16x8*)(wp);
        bf16x8 wb1 = *(const bf16x8*)(wp + 32);
        float bias = (m==0 ? bq : (m==1 ? bk : bv))[col];
        float scale = (m==0) ? qscale : 1.f;
        unsigned short* OPT = m==0 ? qo : (m==1 ? ko : vo);
        #pragma unroll
        for (int rf=0; rf<4; ++rf) {
          f32x4 acc = (f32x4){0.f,0.f,0.f,0.f};
          acc = __builtin_amdgcn_mfma_f32_16x16x32_bf16(a[rf][0], wb0, acc, 0, 0, 0);
          acc = __builtin_amdgcn_mfma_f32_16x16x32_bf16(a[rf][1], wb1, acc, 0, 0, 0);
          #pragma unroll
          for (int j=0;j<4;++j) {
            size_t oi = (size_t)(row_g0 + rf*16 + kq*4 + j)*DM + col;
            OPT[oi] = (unsigned short)f2bf((acc[j] + bias)*scale);
          }
        }
      }
    }
  } else {
    // final LN in place + pool partial (64 rows)
    float mean = mu[srow], inv = iv[srow];
    #pragma unroll
    for (int i=0;i<8;++i) {
      int d = sd8*8 + i;
      hN[srow][d] = (hN[srow][d]-mean)*inv*lns[d] + lnb[d];
    }
    __syncthreads();
    if (tid < 64) {
      float s = 0.f;
      #pragma unroll 4
      for (int rr=0; rr<64; ++rr) s += hN[rr][tid];
      part[bid*64 + tid] = s;
    }
    __syncthreads();

    // last-block finalize: mean-pool + classifier
    if (tid == 0) {
      __threadfence();
      unsigned old = atomicAdd(cnt, 1u);
      lastflag = (old == 255u) ? 1 : 0;
    }
    __syncthreads();
    if (lastflag) {
      __threadfence();
      float* pool = &hN[0][0];     // reuse LDS
      if (tid < 256) {
        int b = tid >> 6, d = tid & 63;
        float sum = 0.f;
        #pragma unroll 8
        for (int i = 0; i < 64; ++i) sum += part[(b*64 + i)*64 + d];
        pool[b*64 + d] = sum * (1.f/4096.f);
      }
      __syncthreads();
      if (tid < 40) {
        int bb = tid / 10, c = tid % 10;
        float acc = bcls[c];
        #pragma unroll
        for (int dd = 0; dd < 64; ++dd) acc = fmaf(pool[bb*64 + dd], wcls[dd*10 + c], acc);
        out[tid] = acc;
      }
    }
  }
}

// ---------- launcher ----------
extern "C" void kernel_launch(void* const* d_in, const int* in_sizes, int n_in,
                              void* d_out, int out_size, void* d_ws, size_t ws_size,
                              hipStream_t stream)
{
  const int*   x    = (const int*)d_in[0];
  const float* emb  = (const float*)d_in[1];
  const float* wq   = (const float*)d_in[2];
  const float* bq   = (const float*)d_in[3];
  const float* wk   = (const float*)d_in[4];
  const float* bk   = (const float*)d_in[5];
  const float* wv   = (const float*)d_in[6];
  const float* bv   = (const float*)d_in[7];
  const float* wo   = (const float*)d_in[8];
  const float* bo   = (const float*)d_in[9];
  const float* ln1s = (const float*)d_in[10];
  const float* ln1b = (const float*)d_in[11];
  const float* ln2s = (const float*)d_in[12];
  const float* ln2b = (const float*)d_in[13];
  const float* w1   = (const float*)d_in[14];
  const float* b1   = (const float*)d_in[15];
  const float* w2   = (const float*)d_in[16];
  const float* b2   = (const float*)d_in[17];
  const float* lnfs = (const float*)d_in[18];
  const float* lnfb = (const float*)d_in[19];
  const float* wcls = (const float*)d_in[20];
  const float* bcls = (const float*)d_in[21];
  float* out = (float*)d_out;

  char* wsb = (char*)d_ws;
  const size_t MB = 1u << 20;
  float* h  = (float*)(wsb);                               // 4 MB f32 [16384][64]
  unsigned short* qA = (unsigned short*)(wsb + 4*MB);      // ping-pong qkv (2 MB each)
  unsigned short* kA = (unsigned short*)(wsb + 6*MB);
  unsigned short* vA = (unsigned short*)(wsb + 8*MB);
  unsigned short* qB = (unsigned short*)(wsb + 10*MB);
  unsigned short* kB = (unsigned short*)(wsb + 12*MB);
  unsigned short* vB = (unsigned short*)(wsb + 14*MB);
  short* wqT = (short*)(wsb + 16*MB);
  short* wkT = (short*)(wsb + 16*MB + 32*1024);
  short* wvT = (short*)(wsb + 16*MB + 64*1024);
  short* woT = (short*)(wsb + 16*MB + 96*1024);
  short* w1T = (short*)(wsb + 16*MB + 128*1024);           // 256 KB
  short* w2T = (short*)(wsb + 16*MB + 384*1024);           // 256 KB
  float* part = (float*)(wsb + 17*MB);                     // 64 KB
  unsigned* cnt = (unsigned*)(wsb + 17*MB + 64*1024);      // 64 B

  hipMemsetAsync((void*)cnt, 0, 64, stream);
  wconv<<<dim3(80,4),256,0,stream>>>(wq,wk,wv,wo,w1,w2, wqT,wkT,wvT,woT,w1T,w2T);

  // head: embed + LN1(l0) + qkv(l0) -> A
  embed_head<<<512,256,0,stream>>>(
      x, emb, ln1s, ln1b, wqT, wkT, wvT, bq, bk, bv, qA, kA, vA, h);

  for (int l = 0; l < 4; ++l) {
    unsigned short* qi = (l & 1) ? qB : qA;
    unsigned short* ki = (l & 1) ? kB : kA;
    unsigned short* vi = (l & 1) ? vB : vA;
    unsigned short* qu = (l & 1) ? qA : qB;
    unsigned short* ku = (l & 1) ? kA : kB;
    unsigned short* vu = (l & 1) ? vA : vB;
    if (l < 3) {
      layer_kernel<false><<<256,512,0,stream>>>(
          qi, ki, vi,
          woT+4096*l, bo+64*l, ln2s+64*l, ln2b+64*l,
          w1T+32768*l, b1+512*l, w2T+32768*l, b2+64*l,
          ln1s+64*(l+1), ln1b+64*(l+1),
          wqT+4096*(l+1), wkT+4096*(l+1), wvT+4096*(l+1),
          bq+64*(l+1), bk+64*(l+1), bv+64*(l+1),
          qu, ku, vu, h, nullptr, nullptr, nullptr, nullptr, nullptr);
    } else {
      layer_kernel<true><<<256,512,0,stream>>>(
          qi, ki, vi,
          woT+4096*l, bo+64*l, ln2s+64*l, ln2b+64*l,
          w1T+32768*l, b1+512*l, w2T+32768*l, b2+64*l,
          lnfs, lnfb,
          nullptr, nullptr, nullptr, nullptr, nullptr, nullptr,
          nullptr, nullptr, nullptr, h, part, wcls, bcls, out, cnt);
    }
  }
}

// Round 17
// 193.578 us; speedup vs baseline: 1.0686x; 1.0686x over previous
//
#include <hip/hip_runtime.h>
#include <hip/hip_bf16.h>

#define DEV __device__ __forceinline__

typedef __attribute__((ext_vector_type(8))) short bf16x8;
typedef __attribute__((ext_vector_type(4))) float f32x4;
typedef __attribute__((ext_vector_type(16))) float f32x16;

// ---------- helpers ----------
DEV short f2bf(float x){ __hip_bfloat16 h = __float2bfloat16(x); return *(short*)&h; }
DEV unsigned pack2bf(float a, float b){
  return (unsigned)(unsigned short)f2bf(a) | ((unsigned)(unsigned short)f2bf(b) << 16);
}
DEV float gelu_fast(float x){
  float z = 0.7978845608028654f*(x + 0.044715f*x*x*x);
  float e = __expf(-2.f*z);
  return x / (1.f + e);
}

#define SB 4096
#define NT 16384
#define DM 64
#define VST 586   // Vs row stride (ushorts); 293 dwords == 5 mod 32 -> reads conflict-free

// ---------- weight convert+transpose: f32 [K][N] -> bf16 [N][K], 32x32 tiles ----------
__global__ __launch_bounds__(256) void wconv(
    const float* __restrict__ wq, const float* __restrict__ wk,
    const float* __restrict__ wv, const float* __restrict__ wo,
    const float* __restrict__ w1, const float* __restrict__ w2,
    short* __restrict__ wqT, short* __restrict__ wkT,
    short* __restrict__ wvT, short* __restrict__ woT,
    short* __restrict__ w1T, short* __restrict__ w2T)
{
  int t = blockIdx.x, l = blockIdx.y;
  const float* src; short* dst; int K, N, kt, nt;
  if (t < 16) {
    int m = t >> 2, sub = t & 3; kt = sub >> 1; nt = sub & 1; K = 64; N = 64;
    const float* s4[4] = {wq, wk, wv, wo};
    short*       d4[4] = {wqT, wkT, wvT, woT};
    src = s4[m] + l*4096; dst = d4[m] + l*4096;
  } else if (t < 48) {
    kt = (t-16) >> 4; nt = (t-16) & 15; K = 64; N = 512;
    src = w1 + l*32768; dst = w1T + l*32768;
  } else {
    kt = (t-48) >> 1; nt = (t-48) & 1; K = 512; N = 64;
    src = w2 + l*32768; dst = w2T + l*32768;
  }
  __shared__ float lds[32][33];
  int tx = threadIdx.x & 31, ty = threadIdx.x >> 5;
  int k0 = kt*32, n0 = nt*32;
  #pragma unroll
  for (int j=0;j<4;++j) lds[ty+8*j][tx] = src[(size_t)(k0+ty+8*j)*N + n0 + tx];
  __syncthreads();
  #pragma unroll
  for (int j=0;j<4;++j) {
    int nn = ty+8*j;
    dst[(size_t)(n0+nn)*K + k0 + tx] = f2bf(lds[tx][nn]);
  }
}

// ---------- building blocks ----------
DEV void make_frags_ln(const float* rowp, float mean, float inv,
    const float* __restrict__ s, const float* __restrict__ b, int kq,
    bf16x8& a0, bf16x8& a1){
  #pragma unroll
  for (int i=0;i<8;++i) a0[i] = f2bf((rowp[kq*8+i]-mean)*inv*s[kq*8+i]+b[kq*8+i]);
  #pragma unroll
  for (int i=0;i<8;++i) a1[i] = f2bf((rowp[32+kq*8+i]-mean)*inv*s[32+kq*8+i]+b[32+kq*8+i]);
}

// ---------- head: embed + posemb + LN1(0) + qkv(0); 32 rows, grid 512 ----------
__global__ __launch_bounds__(256,4) void embed_head(
    const int* __restrict__ x, const float* __restrict__ emb,
    const float* __restrict__ lns, const float* __restrict__ lnb,
    const short* __restrict__ wqT, const short* __restrict__ wkT, const short* __restrict__ wvT,
    const float* __restrict__ bq, const float* __restrict__ bk, const float* __restrict__ bv,
    unsigned short* __restrict__ qo, unsigned short* __restrict__ ko, unsigned short* __restrict__ vo,
    float* __restrict__ h)
{
  __shared__ float hN[32][76];
  __shared__ float mu[32], iv[32];

  const int bid = blockIdx.x;
  const int row_g0 = bid * 32;
  const int tid = threadIdx.x;
  const int w = tid >> 6, lane = tid & 63;
  const int r = lane & 15, kq = lane >> 4;
  const int wr0 = (w >> 1) * 16;
  const int cc0 = (w & 1) * 32;
  const int srow = tid >> 3, sdq = tid & 7;

  // qkv weight prefetch
  bf16x8 qwb[12];
  #pragma unroll
  for (int m=0;m<3;++m){
    const short* WT = m==0?wqT:(m==1?wkT:wvT);
    const short* qp0 = WT + (size_t)(cc0 + r)*64 + kq*8;
    const short* qp1 = WT + (size_t)(cc0 + 16 + r)*64 + kq*8;
    qwb[4*m+0] = *(const bf16x8*)(qp0);
    qwb[4*m+1] = *(const bf16x8*)(qp0 + 32);
    qwb[4*m+2] = *(const bf16x8*)(qp1);
    qwb[4*m+3] = *(const bf16x8*)(qp1 + 32);
  }

  {
    int tg = row_g0 + srow;
    int s = tg & (SB-1);
    int tok = x[tg];
    #pragma unroll
    for (int i=0;i<8;++i) {
      int d = sdq*8 + i;
      float fe = (float)(d & ~1) * (1.0f/64.0f);
      float invk = __expf(-9.210340371976184f * fe);
      float ang = (float)s * invk;
      float pe = (d & 1) ? __cosf(ang) : __sinf(ang);
      float val = emb[tok*DM + d] + pe;
      hN[srow][d] = val;
      h[(size_t)tg*DM + d] = val;
    }
  }
  __syncthreads();

  // LN stats
  {
    const float* p = &hN[srow][sdq*8];
    float v[8];
    float sum = 0.f;
    #pragma unroll
    for (int i=0;i<8;++i){ v[i] = p[i]; sum += v[i]; }
    sum += __shfl_xor(sum, 1, 64); sum += __shfl_xor(sum, 2, 64); sum += __shfl_xor(sum, 4, 64);
    float mean = sum * (1.f/64.f);
    float sq = 0.f;
    #pragma unroll
    for (int i=0;i<8;++i){ float d = v[i]-mean; sq += d*d; }
    sq += __shfl_xor(sq, 1, 64); sq += __shfl_xor(sq, 2, 64); sq += __shfl_xor(sq, 4, 64);
    if (sdq == 0) { mu[srow] = mean; iv[srow] = rsqrtf(sq*(1.f/64.f) + 1e-6f); }
  }
  __syncthreads();

  // qkv
  const float qscale = 0.35355339059327373f;
  bf16x8 a0, a1;
  make_frags_ln(&hN[wr0+r][0], mu[wr0+r], iv[wr0+r], lns, lnb, kq, a0, a1);
  f32x4 aq[2] = {(f32x4){0,0,0,0},(f32x4){0,0,0,0}};
  f32x4 akk[2] = {(f32x4){0,0,0,0},(f32x4){0,0,0,0}};
  f32x4 av[2] = {(f32x4){0,0,0,0},(f32x4){0,0,0,0}};
  #pragma unroll
  for (int ct=0; ct<2; ++ct) {
    aq[ct]  = __builtin_amdgcn_mfma_f32_16x16x32_bf16(a0, qwb[0+2*ct],  aq[ct], 0, 0, 0);
    aq[ct]  = __builtin_amdgcn_mfma_f32_16x16x32_bf16(a1, qwb[1+2*ct],  aq[ct], 0, 0, 0);
    akk[ct] = __builtin_amdgcn_mfma_f32_16x16x32_bf16(a0, qwb[4+2*ct],  akk[ct], 0, 0, 0);
    akk[ct] = __builtin_amdgcn_mfma_f32_16x16x32_bf16(a1, qwb[5+2*ct],  akk[ct], 0, 0, 0);
    av[ct]  = __builtin_amdgcn_mfma_f32_16x16x32_bf16(a0, qwb[8+2*ct],  av[ct], 0, 0, 0);
    av[ct]  = __builtin_amdgcn_mfma_f32_16x16x32_bf16(a1, qwb[9+2*ct],  av[ct], 0, 0, 0);
  }
  #pragma unroll
  for (int ct=0; ct<2; ++ct) {
    int col = cc0 + ct*16 + r;
    float bqv = bq[col], bkv = bk[col], bvv = bv[col];
    #pragma unroll
    for (int j=0;j<4;++j) {
      size_t oi = (size_t)(row_g0 + wr0 + kq*4 + j)*DM + col;
      qo[oi] = (unsigned short)f2bf((aq[ct][j] + bqv)*qscale);
      ko[oi] = (unsigned short)f2bf(akk[ct][j] + bkv);
      vo[oi] = (unsigned short)f2bf(av[ct][j] + bvv);
    }
  }
}

// ---------- merged layer kernel: attention + attnout + FFN + next-qkv ----------
template<bool LAST>
__global__ __launch_bounds__(512,2) void layer_kernel(
    const unsigned short* __restrict__ qin, const unsigned short* __restrict__ kin,
    const unsigned short* __restrict__ vin,
    const short* __restrict__ woT, const float* __restrict__ bo,
    const float* __restrict__ ln2s, const float* __restrict__ ln2b,
    const short* __restrict__ w1T, const float* __restrict__ b1,
    const short* __restrict__ w2T, const float* __restrict__ b2,
    const float* __restrict__ lns, const float* __restrict__ lnb,   // LN1(next) or LNf
    const short* __restrict__ wqT, const short* __restrict__ wkT, const short* __restrict__ wvT,
    const float* __restrict__ bq, const float* __restrict__ bk, const float* __restrict__ bv,
    unsigned short* __restrict__ qo, unsigned short* __restrict__ ko, unsigned short* __restrict__ vo,
    float* __restrict__ h, float* __restrict__ part,
    const float* __restrict__ wcls, const float* __restrict__ bcls,
    float* __restrict__ out, unsigned* __restrict__ cnt)
{
  __shared__ uint4 regA4[4608];   // 73728 B: Ks | (abL + hN + facc)
  __shared__ uint4 regB4[4688];   // 75008 B: Vs | mid
  __shared__ float mu[64], iv[64];
  __shared__ int lastflag;

  unsigned short* Ks  = (unsigned short*)regA4;              // [576][64], swizzled
  unsigned short* abL = (unsigned short*)regA4;              // [64][72] bf16 (post-attn)
  float (*hN)[68]   = (float(*)[68])((char*)regA4 + 9216);
  float (*facc)[68] = (float(*)[68])((char*)regA4 + 26624);
  unsigned short* Vs = (unsigned short*)regB4;               // [64][VST] transposed
  short (*mid)[520]  = (short(*)[520])regB4;

  const int bid = blockIdx.x;
  const int row_g0 = bid * 64;
  const int tid = threadIdx.x;
  const int w = tid >> 6, lane = tid & 63;
  const int r = lane & 15, kq = lane >> 4;
  const int srow = tid >> 3, sd8 = tid & 7;

  const int bbase = row_g0 & ~(SB-1);     // batch base token index
  const int kwin0 = row_g0 - 256;         // global token index of staged key 0

  // ---- stage K [576][64] (swizzled) + V^T [64][VST]; grp-major = coalesced reads ----
  for (int idx = tid; idx < 4608; idx += 512) {
    int e = idx >> 3, grp = idx & 7;
    int g = kwin0 + e;
    uint4 kv = make_uint4(0,0,0,0), vv = make_uint4(0,0,0,0);
    if ((unsigned)(g - bbase) < (unsigned)SB) {
      kv = *(const uint4*)(kin + (size_t)g*DM + grp*8);
      vv = *(const uint4*)(vin + (size_t)g*DM + grp*8);
    }
    *(uint4*)(Ks + e*64 + ((grp ^ (e & 7)) << 3)) = kv;
    const unsigned short* pv = (const unsigned short*)&vv;
    #pragma unroll
    for (int d = 0; d < 8; ++d) Vs[(grp*8 + d)*VST + e] = pv[d];
  }
  __syncthreads();

  // ---- attention: wave w = head w; q-subtiles qs=0,1 ----
  {
    const int qc = lane & 31;
    const int hf = lane >> 5;

    auto attn_job = [&](int qs, f32x16& oacc, float& lacc) {
      const int qglob = row_g0 + qs*32 + qc;
      bf16x8 qfrag = {};
      if (hf == 0) qfrag = *(const bf16x8*)(qin + (size_t)qglob*DM + w*8);
      for (int t = 0; t <= 16; ++t) {
        const int k0l = qs*32 + 32*t;
        const int k0g = kwin0 + k0l;
        if (k0g > bbase + SB-1 || k0g + 31 < bbase) continue;

        bf16x8 kfrag = {};
        if (hf == 0) {
          int e = k0l + qc;
          kfrag = *(const bf16x8*)(Ks + e*64 + ((w ^ (e & 7)) << 3));
        }
        f32x16 s = __builtin_amdgcn_mfma_f32_32x32x16_bf16(kfrag, qfrag, (f32x16){}, 0, 0, 0);

        float pp[16];
        bool needmask = (t == 0) | (t == 16) | (k0g < bbase) | (k0g + 31 > bbase + SB-1);
        if (needmask) {
          #pragma unroll
          for (int rr = 0; rr < 16; ++rr) {
            int klg = k0g + (rr&3) + 8*(rr>>2) + 4*hf;
            bool ok = ((unsigned)(klg - qglob + 256) <= 512u) &&
                      ((unsigned)(klg - bbase) < (unsigned)SB);
            pp[rr] = ok ? __expf(s[rr]) : 0.f;
          }
        } else {
          #pragma unroll
          for (int rr = 0; rr < 16; ++rr) pp[rr] = __expf(s[rr]);
        }
        #pragma unroll
        for (int rr = 0; rr < 16; ++rr) lacc += pp[rr];

        unsigned pk[8];
        #pragma unroll
        for (int j = 0; j < 8; ++j) pk[j] = pack2bf(pp[2*j], pp[2*j+1]);
        unsigned sw[8];
        #pragma unroll
        for (int j = 0; j < 8; ++j) sw[j] = __shfl_xor(pk[j], 32, 64);

        union { unsigned u[4]; bf16x8 v; } pbA;
        pbA.u[0] = hf ? sw[2] : pk[0];
        pbA.u[1] = hf ? sw[3] : pk[1];
        pbA.u[2] = hf ? pk[2] : sw[0];
        pbA.u[3] = hf ? pk[3] : sw[1];
        bf16x8 va1 = {};
        if (qc < 8) va1 = *(const bf16x8*)(Vs + (w*8 + qc)*VST + k0l + 8*hf);
        oacc = __builtin_amdgcn_mfma_f32_32x32x16_bf16(va1, pbA.v, oacc, 0, 0, 0);

        union { unsigned u[4]; bf16x8 v; } pbB;
        pbB.u[0] = hf ? sw[6] : pk[4];
        pbB.u[1] = hf ? sw[7] : pk[5];
        pbB.u[2] = hf ? pk[6] : sw[4];
        pbB.u[3] = hf ? pk[7] : sw[5];
        bf16x8 va2 = {};
        if (qc < 8) va2 = *(const bf16x8*)(Vs + (w*8 + qc)*VST + k0l + 16 + 8*hf);
        oacc = __builtin_amdgcn_mfma_f32_32x32x16_bf16(va2, pbB.v, oacc, 0, 0, 0);
      }
    };

    f32x16 oacc0 = {}; float la0 = 0.f;
    f32x16 oacc1 = {}; float la1 = 0.f;
    attn_job(0, oacc0, la0);
    attn_job(1, oacc1, la1);
    float rcp0 = 1.f / (la0 + __shfl_xor(la0, 32, 64));
    float rcp1 = 1.f / (la1 + __shfl_xor(la1, 32, 64));
    __syncthreads();    // all Ks/Vs reads complete

    unsigned short ov[4];
    #pragma unroll
    for (int j = 0; j < 4; ++j) ov[j] = (unsigned short)f2bf(oacc0[j] * rcp0);
    *(uint2*)(abL + (qc)*72 + w*8 + 4*hf) = *(uint2*)ov;
    #pragma unroll
    for (int j = 0; j < 4; ++j) ov[j] = (unsigned short)f2bf(oacc1[j] * rcp1);
    *(uint2*)(abL + (32 + qc)*72 + w*8 + 4*hf) = *(uint2*)ov;
  }
  __syncthreads();

  // ---- attn-out projection + residual: wave (rh,ct) = 32 rows x 16 cols ----
  {
    const int rh = w >> 2, ct = w & 3;
    const int col = ct*16 + r;
    const short* wp = woT + (size_t)col*64 + kq*8;
    bf16x8 wb0 = *(const bf16x8*)(wp);
    bf16x8 wb1 = *(const bf16x8*)(wp + 32);
    #pragma unroll
    for (int rf=0; rf<2; ++rf) {
      const short* abp = (const short*)(abL + (rh*32 + rf*16 + r)*72 + kq*8);
      bf16x8 a0 = *(const bf16x8*)abp;
      bf16x8 a1 = *(const bf16x8*)(abp + 32);
      f32x4 acc = (f32x4){0.f,0.f,0.f,0.f};
      acc = __builtin_amdgcn_mfma_f32_16x16x32_bf16(a0, wb0, acc, 0, 0, 0);
      acc = __builtin_amdgcn_mfma_f32_16x16x32_bf16(a1, wb1, acc, 0, 0, 0);
      #pragma unroll
      for (int j=0;j<4;++j) {
        int rl = rh*32 + rf*16 + kq*4 + j;
        hN[rl][col] = acc[j] + bo[col] + h[(size_t)(row_g0+rl)*DM + col];
      }
    }
  }
  __syncthreads();

  // LN2 stats
  {
    const float* p = &hN[srow][sd8*8];
    float v[8];
    float sum = 0.f;
    #pragma unroll
    for (int i=0;i<8;++i){ v[i] = p[i]; sum += v[i]; }
    sum += __shfl_xor(sum, 1, 64); sum += __shfl_xor(sum, 2, 64); sum += __shfl_xor(sum, 4, 64);
    float mean = sum * (1.f/64.f);
    float sq = 0.f;
    #pragma unroll
    for (int i=0;i<8;++i){ float d = v[i]-mean; sq += d*d; }
    sq += __shfl_xor(sq, 1, 64); sq += __shfl_xor(sq, 2, 64); sq += __shfl_xor(sq, 4, 64);
    if (sd8 == 0) { mu[srow] = mean; iv[srow] = rsqrtf(sq*(1.f/64.f) + 1e-6f); }
  }
  __syncthreads();

  // ---- fc1: wave w -> cols [64w, 64w+64), all 64 rows ----
  {
    bf16x8 a[4][2];
    #pragma unroll
    for (int rf=0; rf<4; ++rf)
      make_frags_ln(&hN[rf*16 + r][0], mu[rf*16 + r], iv[rf*16 + r], ln2s, ln2b, kq, a[rf][0], a[rf][1]);
    const int gc0 = w*64;
    bf16x8 wb[4][2];
    #pragma unroll
    for (int ct=0; ct<4; ++ct) {
      const short* wp = w1T + (size_t)(gc0 + ct*16 + r)*64 + kq*8;
      wb[ct][0] = *(const bf16x8*)(wp);
      wb[ct][1] = *(const bf16x8*)(wp + 32);
    }
    f32x4 acc1[4][4];
    #pragma unroll
    for (int ct=0;ct<4;++ct)
      #pragma unroll
      for (int rf=0;rf<4;++rf) acc1[ct][rf] = (f32x4){0.f,0.f,0.f,0.f};
    #pragma unroll
    for (int ct=0; ct<4; ++ct)
      #pragma unroll
      for (int rf=0; rf<4; ++rf) {
        acc1[ct][rf] = __builtin_amdgcn_mfma_f32_16x16x32_bf16(a[rf][0], wb[ct][0], acc1[ct][rf], 0, 0, 0);
        acc1[ct][rf] = __builtin_amdgcn_mfma_f32_16x16x32_bf16(a[rf][1], wb[ct][1], acc1[ct][rf], 0, 0, 0);
      }
    __syncthreads();   // Vs region free before mid writes
    #pragma unroll
    for (int ct=0; ct<4; ++ct) {
      int gcol = gc0 + ct*16 + r;
      float bb = b1[gcol];
      #pragma unroll
      for (int rf=0; rf<4; ++rf)
        #pragma unroll
        for (int j=0; j<4; ++j)
          mid[rf*16 + kq*4 + j][gcol] = f2bf(gelu_fast(acc1[ct][rf][j] + bb));
    }
  }
  __syncthreads();

  // ---- fc2: wave (kh = w>>2 K-half, ct2 = w&3 coltile): all 64 rows ----
  {
    const int kh = w >> 2, ct2 = w & 3;
    const int col2 = ct2*16 + r;
    bf16x8 wf[8];
    #pragma unroll
    for (int ks=0; ks<8; ++ks)
      wf[ks] = *(const bf16x8*)(w2T + (size_t)col2*512 + kh*256 + ks*32 + kq*8);
    f32x4 acc2[4];
    #pragma unroll
    for (int rf=0;rf<4;++rf) acc2[rf] = (f32x4){0.f,0.f,0.f,0.f};
    #pragma unroll
    for (int ks=0; ks<8; ++ks)
      #pragma unroll
      for (int rf=0; rf<4; ++rf) {
        bf16x8 af = *(const bf16x8*)(&mid[rf*16 + r][kh*256 + ks*32 + kq*8]);
        acc2[rf] = __builtin_amdgcn_mfma_f32_16x16x32_bf16(af, wf[ks], acc2[rf], 0, 0, 0);
      }
    if (kh == 0) {
      #pragma unroll
      for (int rf=0; rf<4; ++rf)
        #pragma unroll
        for (int j=0;j<4;++j)
          facc[rf*16 + kq*4 + j][col2] = acc2[rf][j];
    }
    __syncthreads();
    if (kh == 1) {
      float bb = b2[col2];
      #pragma unroll
      for (int rf=0; rf<4; ++rf)
        #pragma unroll
        for (int j=0;j<4;++j) {
          int rl = rf*16 + kq*4 + j;
          float val = acc2[rf][j] + facc[rl][col2] + bb + hN[rl][col2];
          hN[rl][col2] = val;
          h[(size_t)(row_g0+rl)*DM + col2] = val;
        }
    }
  }
  __syncthreads();

  // LN stats for LN1(next) / LNf
  {
    const float* p = &hN[srow][sd8*8];
    float v[8];
    float sum = 0.f;
    #pragma unroll
    for (int i=0;i<8;++i){ v[i] = p[i]; sum += v[i]; }
    sum += __shfl_xor(sum, 1, 64); sum += __shfl_xor(sum, 2, 64); sum += __shfl_xor(sum, 4, 64);
    float mean = sum * (1.f/64.f);
    float sq = 0.f;
    #pragma unroll
    for (int i=0;i<8;++i){ float d = v[i]-mean; sq += d*d; }
    sq += __shfl_xor(sq, 1, 64); sq += __shfl_xor(sq, 2, 64); sq += __shfl_xor(sq, 4, 64);
    if (sd8 == 0) { mu[srow] = mean; iv[srow] = rsqrtf(sq*(1.f/64.f) + 1e-6f); }
  }
  __syncthreads();

  if constexpr (!LAST) {
    // qkv of (next) layer: 12 jobs; wave w does jobs {w, w+8}
    const float qscale = 0.35355339059327373f;
    bf16x8 a[4][2];
    #pragma unroll
    for (int rf=0; rf<4; ++rf)
      make_frags_ln(&hN[rf*16 + r][0], mu[rf*16 + r], iv[rf*16 + r], lns, lnb, kq, a[rf][0], a[rf][1]);
    #pragma unroll
    for (int rep=0; rep<2; ++rep) {
      int jj = w + rep*8;
      if (jj < 12) {
        int m = jj >> 2, ct = jj & 3;
        const short* WT = m==0 ? wqT : (m==1 ? wkT : wvT);
        int col = ct*16 + r;
        const short* wp = WT + (size_t)col*64 + kq*8;
        bf16x8 wb0 = *(const bf16x8*)(wp);
        bf16x8 wb1 = *(const bf16x8*)(wp + 32);
        float bias = (m==0 ? bq : (m==1 ? bk : bv))[col];
        float scale = (m==0) ? qscale : 1.f;
        unsigned short* OPT = m==0 ? qo : (m==1 ? ko : vo);
        #pragma unroll
        for (int rf=0; rf<4; ++rf) {
          f32x4 acc = (f32x4){0.f,0.f,0.f,0.f};
          acc = __builtin_amdgcn_mfma_f32_16x16x32_bf16(a[rf][0], wb0, acc, 0, 0, 0);
          acc = __builtin_amdgcn_mfma_f32_16x16x32_bf16(a[rf][1], wb1, acc, 0, 0, 0);
          #pragma unroll
          for (int j=0;j<4;++j) {
            size_t oi = (size_t)(row_g0 + rf*16 + kq*4 + j)*DM + col;
            OPT[oi] = (unsigned short)f2bf((acc[j] + bias)*scale);
          }
        }
      }
    }
  } else {
    // final LN in place + pool partial (64 rows)
    float mean = mu[srow], inv = iv[srow];
    #pragma unroll
    for (int i=0;i<8;++i) {
      int d = sd8*8 + i;
      hN[srow][d] = (hN[srow][d]-mean)*inv*lns[d] + lnb[d];
    }
    __syncthreads();
    if (tid < 64) {
      float s = 0.f;
      #pragma unroll 4
      for (int rr=0; rr<64; ++rr) s += hN[rr][tid];
      part[bid*64 + tid] = s;
    }
    __syncthreads();

    // last-block finalize: mean-pool + classifier
    if (tid == 0) {
      __threadfence();
      unsigned old = atomicAdd(cnt, 1u);
      lastflag = (old == 255u) ? 1 : 0;
    }
    __syncthreads();
    if (lastflag) {
      __threadfence();
      float* pool = &hN[0][0];     // reuse LDS
      if (tid < 256) {
        int b = tid >> 6, d = tid & 63;
        float sum = 0.f;
        #pragma unroll 8
        for (int i = 0; i < 64; ++i) sum += part[(b*64 + i)*64 + d];
        pool[b*64 + d] = sum * (1.f/4096.f);
      }
      __syncthreads();
      if (tid < 40) {
        int bb = tid / 10, c = tid % 10;
        float acc = bcls[c];
        #pragma unroll
        for (int dd = 0; dd < 64; ++dd) acc = fmaf(pool[bb*64 + dd], wcls[dd*10 + c], acc);
        out[tid] = acc;
      }
    }
  }
}

// ---------- launcher ----------
extern "C" void kernel_launch(void* const* d_in, const int* in_sizes, int n_in,
                              void* d_out, int out_size, void* d_ws, size_t ws_size,
                              hipStream_t stream)
{
  const int*   x    = (const int*)d_in[0];
  const float* emb  = (const float*)d_in[1];
  const float* wq   = (const float*)d_in[2];
  const float* bq   = (const float*)d_in[3];
  const float* wk   = (const float*)d_in[4];
  const float* bk   = (const float*)d_in[5];
  const float* wv   = (const float*)d_in[6];
  const float* bv   = (const float*)d_in[7];
  const float* wo   = (const float*)d_in[8];
  const float* bo   = (const float*)d_in[9];
  const float* ln1s = (const float*)d_in[10];
  const float* ln1b = (const float*)d_in[11];
  const float* ln2s = (const float*)d_in[12];
  const float* ln2b = (const float*)d_in[13];
  const float* w1   = (const float*)d_in[14];
  const float* b1   = (const float*)d_in[15];
  const float* w2   = (const float*)d_in[16];
  const float* b2   = (const float*)d_in[17];
  const float* lnfs = (const float*)d_in[18];
  const float* lnfb = (const float*)d_in[19];
  const float* wcls = (const float*)d_in[20];
  const float* bcls = (const float*)d_in[21];
  float* out = (float*)d_out;

  char* wsb = (char*)d_ws;
  const size_t MB = 1u << 20;
  float* h  = (float*)(wsb);                               // 4 MB f32 [16384][64]
  unsigned short* qA = (unsigned short*)(wsb + 4*MB);      // ping-pong qkv (2 MB each)
  unsigned short* kA = (unsigned short*)(wsb + 6*MB);
  unsigned short* vA = (unsigned short*)(wsb + 8*MB);
  unsigned short* qB = (unsigned short*)(wsb + 10*MB);
  unsigned short* kB = (unsigned short*)(wsb + 12*MB);
  unsigned short* vB = (unsigned short*)(wsb + 14*MB);
  short* wqT = (short*)(wsb + 16*MB);
  short* wkT = (short*)(wsb + 16*MB + 32*1024);
  short* wvT = (short*)(wsb + 16*MB + 64*1024);
  short* woT = (short*)(wsb + 16*MB + 96*1024);
  short* w1T = (short*)(wsb + 16*MB + 128*1024);           // 256 KB
  short* w2T = (short*)(wsb + 16*MB + 384*1024);           // 256 KB
  float* part = (float*)(wsb + 17*MB);                     // 64 KB
  unsigned* cnt = (unsigned*)(wsb + 17*MB + 64*1024);      // 64 B

  hipMemsetAsync((void*)cnt, 0, 64, stream);
  wconv<<<dim3(80,4),256,0,stream>>>(wq,wk,wv,wo,w1,w2, wqT,wkT,wvT,woT,w1T,w2T);

  // head: embed + LN1(l0) + qkv(l0) -> A
  embed_head<<<512,256,0,stream>>>(
      x, emb, ln1s, ln1b, wqT, wkT, wvT, bq, bk, bv, qA, kA, vA, h);

  for (int l = 0; l < 4; ++l) {
    unsigned short* qi = (l & 1) ? qB : qA;
    unsigned short* ki = (l & 1) ? kB : kA;
    unsigned short* vi = (l & 1) ? vB : vA;
    unsigned short* qu = (l & 1) ? qA : qB;
    unsigned short* ku = (l & 1) ? kA : kB;
    unsigned short* vu = (l & 1) ? vA : vB;
    if (l < 3) {
      layer_kernel<false><<<256,512,0,stream>>>(
          qi, ki, vi,
          woT+4096*l, bo+64*l, ln2s+64*l, ln2b+64*l,
          w1T+32768*l, b1+512*l, w2T+32768*l, b2+64*l,
          ln1s+64*(l+1), ln1b+64*(l+1),
          wqT+4096*(l+1), wkT+4096*(l+1), wvT+4096*(l+1),
          bq+64*(l+1), bk+64*(l+1), bv+64*(l+1),
          qu, ku, vu, h, nullptr, nullptr, nullptr, nullptr, nullptr);
    } else {
      layer_kernel<true><<<256,512,0,stream>>>(
          qi, ki, vi,
          woT+4096*l, bo+64*l, ln2s+64*l, ln2b+64*l,
          w1T+32768*l, b1+512*l, w2T+32768*l, b2+64*l,
          lnfs, lnfb,
          nullptr, nullptr, nullptr, nullptr, nullptr, nullptr,
          nullptr, nullptr, nullptr, h, part, wcls, bcls, out, cnt);
    }
  }
}

// Round 18
// 184.400 us; speedup vs baseline: 1.1218x; 1.0498x over previous
//
#include <hip/hip_runtime.h>
#include <hip/hip_bf16.h>

#define DEV __device__ __forceinline__

typedef __attribute__((ext_vector_type(8))) short bf16x8;
typedef __attribute__((ext_vector_type(4))) float f32x4;
typedef __attribute__((ext_vector_type(16))) float f32x16;

// ---------- helpers ----------
DEV short f2bf(float x){ __hip_bfloat16 h = __float2bfloat16(x); return *(short*)&h; }
DEV unsigned pack2bf(float a, float b){
  return (unsigned)(unsigned short)f2bf(a) | ((unsigned)(unsigned short)f2bf(b) << 16);
}
DEV float gelu_fast(float x){
  float z = 0.7978845608028654f*(x + 0.044715f*x*x*x);
  float e = __expf(-2.f*z);
  return x / (1.f + e);
}

#define SB 4096
#define NT 16384
#define DM 64
#define VST 586   // Vs row stride (ushorts); 293 dwords == 5 mod 32 -> writes 2-way, reads conflict-free

// ---------- weight convert+transpose: f32 [K][N] -> bf16 [N][K], 32x32 tiles ----------
__global__ __launch_bounds__(256) void wconv(
    const float* __restrict__ wq, const float* __restrict__ wk,
    const float* __restrict__ wv, const float* __restrict__ wo,
    const float* __restrict__ w1, const float* __restrict__ w2,
    short* __restrict__ wqT, short* __restrict__ wkT,
    short* __restrict__ wvT, short* __restrict__ woT,
    short* __restrict__ w1T, short* __restrict__ w2T)
{
  int t = blockIdx.x, l = blockIdx.y;
  const float* src; short* dst; int K, N, kt, nt;
  if (t < 16) {
    int m = t >> 2, sub = t & 3; kt = sub >> 1; nt = sub & 1; K = 64; N = 64;
    const float* s4[4] = {wq, wk, wv, wo};
    short*       d4[4] = {wqT, wkT, wvT, woT};
    src = s4[m] + l*4096; dst = d4[m] + l*4096;
  } else if (t < 48) {
    kt = (t-16) >> 4; nt = (t-16) & 15; K = 64; N = 512;
    src = w1 + l*32768; dst = w1T + l*32768;
  } else {
    kt = (t-48) >> 1; nt = (t-48) & 1; K = 512; N = 64;
    src = w2 + l*32768; dst = w2T + l*32768;
  }
  __shared__ float lds[32][33];
  int tx = threadIdx.x & 31, ty = threadIdx.x >> 5;
  int k0 = kt*32, n0 = nt*32;
  #pragma unroll
  for (int j=0;j<4;++j) lds[ty+8*j][tx] = src[(size_t)(k0+ty+8*j)*N + n0 + tx];
  __syncthreads();
  #pragma unroll
  for (int j=0;j<4;++j) {
    int nn = ty+8*j;
    dst[(size_t)(n0+nn)*K + k0 + tx] = f2bf(lds[tx][nn]);
  }
}

// ---------- building blocks ----------
DEV void make_frags_ln(const float* rowp, float mean, float inv,
    const float* __restrict__ s, const float* __restrict__ b, int kq,
    bf16x8& a0, bf16x8& a1){
  #pragma unroll
  for (int i=0;i<8;++i) a0[i] = f2bf((rowp[kq*8+i]-mean)*inv*s[kq*8+i]+b[kq*8+i]);
  #pragma unroll
  for (int i=0;i<8;++i) a1[i] = f2bf((rowp[32+kq*8+i]-mean)*inv*s[32+kq*8+i]+b[32+kq*8+i]);
}

// ---------- merged layer kernel: attention + attnout + FFN + next-qkv ----------
// 64 rows/block, 8 waves, grid 256. K staged [576][64] bf16 (XOR-swizzled 16B units),
// V staged transposed [64][VST]. Attention: wave = head, 2 q-subtiles of 32.
template<bool EMBED, bool LAST>
__global__ __launch_bounds__(512,2) void layer_kernel(
    const int* __restrict__ x, const float* __restrict__ emb,
    const unsigned short* __restrict__ qin, const unsigned short* __restrict__ kin,
    const unsigned short* __restrict__ vin,
    const short* __restrict__ woT, const float* __restrict__ bo,
    const float* __restrict__ ln2s, const float* __restrict__ ln2b,
    const short* __restrict__ w1T, const float* __restrict__ b1,
    const short* __restrict__ w2T, const float* __restrict__ b2,
    const float* __restrict__ lns, const float* __restrict__ lnb,   // LN1(next) or LNf
    const short* __restrict__ wqT, const short* __restrict__ wkT, const short* __restrict__ wvT,
    const float* __restrict__ bq, const float* __restrict__ bk, const float* __restrict__ bv,
    unsigned short* __restrict__ qo, unsigned short* __restrict__ ko, unsigned short* __restrict__ vo,
    float* __restrict__ h, float* __restrict__ part)
{
  __shared__ uint4 regA4[4608];   // 73728 B: Ks | (abL + hN + facc)
  __shared__ uint4 regB4[4688];   // 75008 B: Vs | mid
  __shared__ float mu[64], iv[64];

  unsigned short* Ks  = (unsigned short*)regA4;              // [576][64], swizzled
  unsigned short* abL = (unsigned short*)regA4;              // [64][72] bf16 (post-attn)
  float (*hN)[68]   = (float(*)[68])((char*)regA4 + 9216);
  float (*facc)[68] = (float(*)[68])((char*)regA4 + 26624);
  unsigned short* Vs = (unsigned short*)regB4;               // [64][VST] transposed
  short (*mid)[520]  = (short(*)[520])regB4;

  const int bid = blockIdx.x;
  const int row_g0 = bid * 64;
  const int tid = threadIdx.x;
  const int w = tid >> 6, lane = tid & 63;
  const int r = lane & 15, kq = lane >> 4;
  const int srow = tid >> 3, sd8 = tid & 7;

  if constexpr (EMBED) {
    int tg = row_g0 + srow;
    int s = tg & (SB-1);
    int tok = x[tg];
    #pragma unroll
    for (int i=0;i<8;++i) {
      int d = sd8*8 + i;
      float fe = (float)(d & ~1) * (1.0f/64.0f);
      float invk = __expf(-9.210340371976184f * fe);
      float ang = (float)s * invk;
      float pe = (d & 1) ? __cosf(ang) : __sinf(ang);
      float val = emb[tok*DM + d] + pe;
      hN[srow][d] = val;
      h[(size_t)tg*DM + d] = val;
    }
  } else {
    const int bbase = row_g0 & ~(SB-1);     // batch base token index
    const int kwin0 = row_g0 - 256;         // global token index of staged key 0

    // ---- stage K [576][64] (swizzled) + V^T [64][VST]; grp-major = coalesced reads ----
    for (int idx = tid; idx < 4608; idx += 512) {
      int e = idx >> 3, grp = idx & 7;
      int g = kwin0 + e;
      uint4 kv = make_uint4(0,0,0,0), vv = make_uint4(0,0,0,0);
      if ((unsigned)(g - bbase) < (unsigned)SB) {
        kv = *(const uint4*)(kin + (size_t)g*DM + grp*8);
        vv = *(const uint4*)(vin + (size_t)g*DM + grp*8);
      }
      *(uint4*)(Ks + e*64 + ((grp ^ (e & 7)) << 3)) = kv;
      const unsigned short* pv = (const unsigned short*)&vv;
      #pragma unroll
      for (int d = 0; d < 8; ++d) Vs[(grp*8 + d)*VST + e] = pv[d];
    }
    __syncthreads();

    // ---- attention: wave w = head w; q-subtiles qs=0,1 ----
    const int qc = lane & 31;
    const int hf = lane >> 5;

    auto attn_job = [&](int qs, f32x16& oacc, float& lacc) {
      const int qglob = row_g0 + qs*32 + qc;
      bf16x8 qfrag = {};
      if (hf == 0) qfrag = *(const bf16x8*)(qin + (size_t)qglob*DM + w*8);
      for (int t = 0; t <= 16; ++t) {
        const int k0l = qs*32 + 32*t;
        const int k0g = kwin0 + k0l;
        if (k0g > bbase + SB-1 || k0g + 31 < bbase) continue;

        bf16x8 kfrag = {};
        if (hf == 0) {
          int e = k0l + qc;
          kfrag = *(const bf16x8*)(Ks + e*64 + ((w ^ (e & 7)) << 3));
        }
        f32x16 s = __builtin_amdgcn_mfma_f32_32x32x16_bf16(kfrag, qfrag, (f32x16){}, 0, 0, 0);

        float pp[16];
        bool needmask = (t == 0) | (t == 16) | (k0g < bbase) | (k0g + 31 > bbase + SB-1);
        if (needmask) {
          #pragma unroll
          for (int rr = 0; rr < 16; ++rr) {
            int klg = k0g + (rr&3) + 8*(rr>>2) + 4*hf;
            bool ok = ((unsigned)(klg - qglob + 256) <= 512u) &&
                      ((unsigned)(klg - bbase) < (unsigned)SB);
            pp[rr] = ok ? __expf(s[rr]) : 0.f;
          }
        } else {
          #pragma unroll
          for (int rr = 0; rr < 16; ++rr) pp[rr] = __expf(s[rr]);
        }
        #pragma unroll
        for (int rr = 0; rr < 16; ++rr) lacc += pp[rr];

        unsigned pk[8];
        #pragma unroll
        for (int j = 0; j < 8; ++j) pk[j] = pack2bf(pp[2*j], pp[2*j+1]);
        unsigned sw[8];
        #pragma unroll
        for (int j = 0; j < 8; ++j) sw[j] = __shfl_xor(pk[j], 32, 64);

        union { unsigned u[4]; bf16x8 v; } pbA;
        pbA.u[0] = hf ? sw[2] : pk[0];
        pbA.u[1] = hf ? sw[3] : pk[1];
        pbA.u[2] = hf ? pk[2] : sw[0];
        pbA.u[3] = hf ? pk[3] : sw[1];
        bf16x8 va1 = {};
        if (qc < 8) va1 = *(const bf16x8*)(Vs + (w*8 + qc)*VST + k0l + 8*hf);
        oacc = __builtin_amdgcn_mfma_f32_32x32x16_bf16(va1, pbA.v, oacc, 0, 0, 0);

        union { unsigned u[4]; bf16x8 v; } pbB;
        pbB.u[0] = hf ? sw[6] : pk[4];
        pbB.u[1] = hf ? sw[7] : pk[5];
        pbB.u[2] = hf ? pk[6] : sw[4];
        pbB.u[3] = hf ? pk[7] : sw[5];
        bf16x8 va2 = {};
        if (qc < 8) va2 = *(const bf16x8*)(Vs + (w*8 + qc)*VST + k0l + 16 + 8*hf);
        oacc = __builtin_amdgcn_mfma_f32_32x32x16_bf16(va2, pbB.v, oacc, 0, 0, 0);
      }
    };

    f32x16 oacc0 = {}; float la0 = 0.f;
    f32x16 oacc1 = {}; float la1 = 0.f;
    attn_job(0, oacc0, la0);
    attn_job(1, oacc1, la1);
    float rcp0 = 1.f / (la0 + __shfl_xor(la0, 32, 64));
    float rcp1 = 1.f / (la1 + __shfl_xor(la1, 32, 64));
    __syncthreads();    // all Ks/Vs reads complete

    // write attention output bf16 into abL (overlays Ks region)
    {
      unsigned short ov[4];
      #pragma unroll
      for (int j = 0; j < 4; ++j) ov[j] = (unsigned short)f2bf(oacc0[j] * rcp0);
      *(uint2*)(abL + (qc)*72 + w*8 + 4*hf) = *(uint2*)ov;
      #pragma unroll
      for (int j = 0; j < 4; ++j) ov[j] = (unsigned short)f2bf(oacc1[j] * rcp1);
      *(uint2*)(abL + (32 + qc)*72 + w*8 + 4*hf) = *(uint2*)ov;
    }
    __syncthreads();

    // ---- attn-out projection + residual: wave (rh,ct) = 32 rows x 16 cols ----
    {
      const int rh = w >> 2, ct = w & 3;
      const int col = ct*16 + r;
      const short* wp = woT + (size_t)col*64 + kq*8;
      bf16x8 wb0 = *(const bf16x8*)(wp);
      bf16x8 wb1 = *(const bf16x8*)(wp + 32);
      #pragma unroll
      for (int rf=0; rf<2; ++rf) {
        const short* abp = (const short*)(abL + (rh*32 + rf*16 + r)*72 + kq*8);
        bf16x8 a0 = *(const bf16x8*)abp;
        bf16x8 a1 = *(const bf16x8*)(abp + 32);
        f32x4 acc = (f32x4){0.f,0.f,0.f,0.f};
        acc = __builtin_amdgcn_mfma_f32_16x16x32_bf16(a0, wb0, acc, 0, 0, 0);
        acc = __builtin_amdgcn_mfma_f32_16x16x32_bf16(a1, wb1, acc, 0, 0, 0);
        #pragma unroll
        for (int j=0;j<4;++j) {
          int rl = rh*32 + rf*16 + kq*4 + j;
          hN[rl][col] = acc[j] + bo[col] + h[(size_t)(row_g0+rl)*DM + col];
        }
      }
    }
  }
  __syncthreads();

  // LN stats (LN1 for EMBED, LN2 otherwise)
  {
    const float* p = &hN[srow][sd8*8];
    float v[8];
    float sum = 0.f;
    #pragma unroll
    for (int i=0;i<8;++i){ v[i] = p[i]; sum += v[i]; }
    sum += __shfl_xor(sum, 1, 64); sum += __shfl_xor(sum, 2, 64); sum += __shfl_xor(sum, 4, 64);
    float mean = sum * (1.f/64.f);
    float sq = 0.f;
    #pragma unroll
    for (int i=0;i<8;++i){ float d = v[i]-mean; sq += d*d; }
    sq += __shfl_xor(sq, 1, 64); sq += __shfl_xor(sq, 2, 64); sq += __shfl_xor(sq, 4, 64);
    if (sd8 == 0) { mu[srow] = mean; iv[srow] = rsqrtf(sq*(1.f/64.f) + 1e-6f); }
  }
  __syncthreads();

  if constexpr (!EMBED) {
    // ---- fc1: wave w -> cols [64w, 64w+64), all 64 rows ----
    {
      bf16x8 a[4][2];
      #pragma unroll
      for (int rf=0; rf<4; ++rf)
        make_frags_ln(&hN[rf*16 + r][0], mu[rf*16 + r], iv[rf*16 + r], ln2s, ln2b, kq, a[rf][0], a[rf][1]);
      const int gc0 = w*64;
      bf16x8 wb[4][2];
      #pragma unroll
      for (int ct=0; ct<4; ++ct) {
        const short* wp = w1T + (size_t)(gc0 + ct*16 + r)*64 + kq*8;
        wb[ct][0] = *(const bf16x8*)(wp);
        wb[ct][1] = *(const bf16x8*)(wp + 32);
      }
      f32x4 acc1[4][4];
      #pragma unroll
      for (int ct=0;ct<4;++ct)
        #pragma unroll
        for (int rf=0;rf<4;++rf) acc1[ct][rf] = (f32x4){0.f,0.f,0.f,0.f};
      #pragma unroll
      for (int ct=0; ct<4; ++ct)
        #pragma unroll
        for (int rf=0; rf<4; ++rf) {
          acc1[ct][rf] = __builtin_amdgcn_mfma_f32_16x16x32_bf16(a[rf][0], wb[ct][0], acc1[ct][rf], 0, 0, 0);
          acc1[ct][rf] = __builtin_amdgcn_mfma_f32_16x16x32_bf16(a[rf][1], wb[ct][1], acc1[ct][rf], 0, 0, 0);
        }
      __syncthreads();   // Vs region free before mid writes
      #pragma unroll
      for (int ct=0; ct<4; ++ct) {
        int gcol = gc0 + ct*16 + r;
        float bb = b1[gcol];
        #pragma unroll
        for (int rf=0; rf<4; ++rf)
          #pragma unroll
          for (int j=0; j<4; ++j)
            mid[rf*16 + kq*4 + j][gcol] = f2bf(gelu_fast(acc1[ct][rf][j] + bb));
      }
    }
    __syncthreads();

    // ---- fc2: wave (kh = w>>2 K-half, ct2 = w&3 coltile): all 64 rows ----
    {
      const int kh = w >> 2, ct2 = w & 3;
      const int col2 = ct2*16 + r;
      bf16x8 wf[8];
      #pragma unroll
      for (int ks=0; ks<8; ++ks)
        wf[ks] = *(const bf16x8*)(w2T + (size_t)col2*512 + kh*256 + ks*32 + kq*8);
      f32x4 acc2[4];
      #pragma unroll
      for (int rf=0;rf<4;++rf) acc2[rf] = (f32x4){0.f,0.f,0.f,0.f};
      #pragma unroll
      for (int ks=0; ks<8; ++ks)
        #pragma unroll
        for (int rf=0; rf<4; ++rf) {
          bf16x8 af = *(const bf16x8*)(&mid[rf*16 + r][kh*256 + ks*32 + kq*8]);
          acc2[rf] = __builtin_amdgcn_mfma_f32_16x16x32_bf16(af, wf[ks], acc2[rf], 0, 0, 0);
        }
      if (kh == 0) {
        #pragma unroll
        for (int rf=0; rf<4; ++rf)
          #pragma unroll
          for (int j=0;j<4;++j)
            facc[rf*16 + kq*4 + j][col2] = acc2[rf][j];
      }
      __syncthreads();
      if (kh == 1) {
        float bb = b2[col2];
        #pragma unroll
        for (int rf=0; rf<4; ++rf)
          #pragma unroll
          for (int j=0;j<4;++j) {
            int rl = rf*16 + kq*4 + j;
            float val = acc2[rf][j] + facc[rl][col2] + bb + hN[rl][col2];
            hN[rl][col2] = val;
            h[(size_t)(row_g0+rl)*DM + col2] = val;
          }
      }
    }
    __syncthreads();

    // LN stats for LN1(next) / LNf
    {
      const float* p = &hN[srow][sd8*8];
      float v[8];
      float sum = 0.f;
      #pragma unroll
      for (int i=0;i<8;++i){ v[i] = p[i]; sum += v[i]; }
      sum += __shfl_xor(sum, 1, 64); sum += __shfl_xor(sum, 2, 64); sum += __shfl_xor(sum, 4, 64);
      float mean = sum * (1.f/64.f);
      float sq = 0.f;
      #pragma unroll
      for (int i=0;i<8;++i){ float d = v[i]-mean; sq += d*d; }
      sq += __shfl_xor(sq, 1, 64); sq += __shfl_xor(sq, 2, 64); sq += __shfl_xor(sq, 4, 64);
      if (sd8 == 0) { mu[srow] = mean; iv[srow] = rsqrtf(sq*(1.f/64.f) + 1e-6f); }
    }
    __syncthreads();
  }

  if constexpr (!LAST) {
    // qkv of (next) layer: 12 jobs; wave w does jobs {w, w+8}
    const float qscale = 0.35355339059327373f;
    bf16x8 a[4][2];
    #pragma unroll
    for (int rf=0; rf<4; ++rf)
      make_frags_ln(&hN[rf*16 + r][0], mu[rf*16 + r], iv[rf*16 + r], lns, lnb, kq, a[rf][0], a[rf][1]);
    #pragma unroll
    for (int rep=0; rep<2; ++rep) {
      int jj = w + rep*8;
      if (jj < 12) {
        int m = jj >> 2, ct = jj & 3;
        const short* WT = m==0 ? wqT : (m==1 ? wkT : wvT);
        int col = ct*16 + r;
        const short* wp = WT + (size_t)col*64 + kq*8;
        bf16x8 wb0 = *(const bf16x8*)(wp);
        bf16x8 wb1 = *(const bf16x8*)(wp + 32);
        float bias = (m==0 ? bq : (m==1 ? bk : bv))[col];
        float scale = (m==0) ? qscale : 1.f;
        unsigned short* OPT = m==0 ? qo : (m==1 ? ko : vo);
        #pragma unroll
        for (int rf=0; rf<4; ++rf) {
          f32x4 acc = (f32x4){0.f,0.f,0.f,0.f};
          acc = __builtin_amdgcn_mfma_f32_16x16x32_bf16(a[rf][0], wb0, acc, 0, 0, 0);
          acc = __builtin_amdgcn_mfma_f32_16x16x32_bf16(a[rf][1], wb1, acc, 0, 0, 0);
          #pragma unroll
          for (int j=0;j<4;++j) {
            size_t oi = (size_t)(row_g0 + rf*16 + kq*4 + j)*DM + col;
            OPT[oi] = (unsigned short)f2bf((acc[j] + bias)*scale);
          }
        }
      }
    }
  } else {
    // final LN in place + pool partial (64 rows)
    float mean = mu[srow], inv = iv[srow];
    #pragma unroll
    for (int i=0;i<8;++i) {
      int d = sd8*8 + i;
      hN[srow][d] = (hN[srow][d]-mean)*inv*lns[d] + lnb[d];
    }
    __syncthreads();
    if (tid < 64) {
      float s = 0.f;
      #pragma unroll 4
      for (int rr=0; rr<64; ++rr) s += hN[rr][tid];
      part[bid*64 + tid] = s;
    }
  }
}

// ---------- pool finalize + classifier ----------
__global__ __launch_bounds__(256) void pool_finalize(const float* __restrict__ part,
    const float* __restrict__ wcls, const float* __restrict__ bcls, float* __restrict__ out)
{
  int tid = threadIdx.x;
  int b = tid >> 6, d = tid & 63;
  float sum = 0.f;
  #pragma unroll 8
  for (int i = 0; i < 64; ++i) sum += part[(b*64 + i)*64 + d];
  __shared__ float pooled[4][64];
  pooled[b][d] = sum * (1.f/4096.f);
  __syncthreads();
  if (tid < 40) {
    int bb = tid / 10, c = tid % 10;
    float acc = bcls[c];
    #pragma unroll
    for (int dd = 0; dd < 64; ++dd) acc = fmaf(pooled[bb][dd], wcls[dd*10 + c], acc);
    out[tid] = acc;
  }
}

// ---------- launcher ----------
extern "C" void kernel_launch(void* const* d_in, const int* in_sizes, int n_in,
                              void* d_out, int out_size, void* d_ws, size_t ws_size,
                              hipStream_t stream)
{
  const int*   x    = (const int*)d_in[0];
  const float* emb  = (const float*)d_in[1];
  const float* wq   = (const float*)d_in[2];
  const float* bq   = (const float*)d_in[3];
  const float* wk   = (const float*)d_in[4];
  const float* bk   = (const float*)d_in[5];
  const float* wv   = (const float*)d_in[6];
  const float* bv   = (const float*)d_in[7];
  const float* wo   = (const float*)d_in[8];
  const float* bo   = (const float*)d_in[9];
  const float* ln1s = (const float*)d_in[10];
  const float* ln1b = (const float*)d_in[11];
  const float* ln2s = (const float*)d_in[12];
  const float* ln2b = (const float*)d_in[13];
  const float* w1   = (const float*)d_in[14];
  const float* b1   = (const float*)d_in[15];
  const float* w2   = (const float*)d_in[16];
  const float* b2   = (const float*)d_in[17];
  const float* lnfs = (const float*)d_in[18];
  const float* lnfb = (const float*)d_in[19];
  const float* wcls = (const float*)d_in[20];
  const float* bcls = (const float*)d_in[21];
  float* out = (float*)d_out;

  char* wsb = (char*)d_ws;
  const size_t MB = 1u << 20;
  float* h  = (float*)(wsb);                               // 4 MB f32 [16384][64]
  unsigned short* qA = (unsigned short*)(wsb + 4*MB);      // ping-pong qkv (2 MB each)
  unsigned short* kA = (unsigned short*)(wsb + 6*MB);
  unsigned short* vA = (unsigned short*)(wsb + 8*MB);
  unsigned short* qB = (unsigned short*)(wsb + 10*MB);
  unsigned short* kB = (unsigned short*)(wsb + 12*MB);
  unsigned short* vB = (unsigned short*)(wsb + 14*MB);
  short* wqT = (short*)(wsb + 16*MB);
  short* wkT = (short*)(wsb + 16*MB + 32*1024);
  short* wvT = (short*)(wsb + 16*MB + 64*1024);
  short* woT = (short*)(wsb + 16*MB + 96*1024);
  short* w1T = (short*)(wsb + 16*MB + 128*1024);           // 256 KB
  short* w2T = (short*)(wsb + 16*MB + 384*1024);           // 256 KB
  float* part = (float*)(wsb + 17*MB);                     // 64 KB

  wconv<<<dim3(80,4),256,0,stream>>>(wq,wk,wv,wo,w1,w2, wqT,wkT,wvT,woT,w1T,w2T);

  // head: embed + LN1(l0) + qkv(l0) -> A
  layer_kernel<true,false><<<256,512,0,stream>>>(
      x, emb, nullptr, nullptr, nullptr,
      nullptr, nullptr, nullptr, nullptr,
      nullptr, nullptr, nullptr, nullptr,
      ln1s, ln1b,
      wqT, wkT, wvT, bq, bk, bv,
      qA, kA, vA, h, nullptr);

  for (int l = 0; l < 4; ++l) {
    unsigned short* qi = (l & 1) ? qB : qA;
    unsigned short* ki = (l & 1) ? kB : kA;
    unsigned short* vi = (l & 1) ? vB : vA;
    unsigned short* qu = (l & 1) ? qA : qB;
    unsigned short* ku = (l & 1) ? kA : kB;
    unsigned short* vu = (l & 1) ? vA : vB;
    if (l < 3) {
      layer_kernel<false,false><<<256,512,0,stream>>>(
          nullptr, nullptr, qi, ki, vi,
          woT+4096*l, bo+64*l, ln2s+64*l, ln2b+64*l,
          w1T+32768*l, b1+512*l, w2T+32768*l, b2+64*l,
          ln1s+64*(l+1), ln1b+64*(l+1),
          wqT+4096*(l+1), wkT+4096*(l+1), wvT+4096*(l+1),
          bq+64*(l+1), bk+64*(l+1), bv+64*(l+1),
          qu, ku, vu, h, nullptr);
    } else {
      layer_kernel<false,true><<<256,512,0,stream>>>(
          nullptr, nullptr, qi, ki, vi,
          woT+4096*l, bo+64*l, ln2s+64*l, ln2b+64*l,
          w1T+32768*l, b1+512*l, w2T+32768*l, b2+64*l,
          lnfs, lnfb,
          nullptr, nullptr, nullptr, nullptr, nullptr, nullptr,
          nullptr, nullptr, nullptr, h, part);
    }
  }
  pool_finalize<<<1,256,0,stream>>>(part, wcls, bcls, out);
}

// Round 19
// 182.543 us; speedup vs baseline: 1.1332x; 1.0102x over previous
//
#include <hip/hip_runtime.h>
#include <hip/hip_bf16.h>

#define DEV __device__ __forceinline__

typedef __attribute__((ext_vector_type(8))) short bf16x8;
typedef __attribute__((ext_vector_type(4))) float f32x4;
typedef __attribute__((ext_vector_type(16))) float f32x16;

// ---------- helpers ----------
DEV short f2bf(float x){ __hip_bfloat16 h = __float2bfloat16(x); return *(short*)&h; }
DEV unsigned pack2bf(float a, float b){
  return (unsigned)(unsigned short)f2bf(a) | ((unsigned)(unsigned short)f2bf(b) << 16);
}
DEV float gelu_fast(float x){
  float z = 0.7978845608028654f*(x + 0.044715f*x*x*x);
  float e = __expf(-2.f*z);
  return x / (1.f + e);
}

#define SB 4096
#define NT 16384
#define DM 64
#define VST 586   // Vs row stride (ushorts); 293 dwords == 5 mod 32 -> writes 2-way, reads conflict-free

// ---------- weight convert+transpose: f32 [K][N] -> bf16 [N][K], 32x32 tiles ----------
__global__ __launch_bounds__(256) void wconv(
    const float* __restrict__ wq, const float* __restrict__ wk,
    const float* __restrict__ wv, const float* __restrict__ wo,
    const float* __restrict__ w1, const float* __restrict__ w2,
    short* __restrict__ wqT, short* __restrict__ wkT,
    short* __restrict__ wvT, short* __restrict__ woT,
    short* __restrict__ w1T, short* __restrict__ w2T)
{
  int t = blockIdx.x, l = blockIdx.y;
  const float* src; short* dst; int K, N, kt, nt;
  if (t < 16) {
    int m = t >> 2, sub = t & 3; kt = sub >> 1; nt = sub & 1; K = 64; N = 64;
    const float* s4[4] = {wq, wk, wv, wo};
    short*       d4[4] = {wqT, wkT, wvT, woT};
    src = s4[m] + l*4096; dst = d4[m] + l*4096;
  } else if (t < 48) {
    kt = (t-16) >> 4; nt = (t-16) & 15; K = 64; N = 512;
    src = w1 + l*32768; dst = w1T + l*32768;
  } else {
    kt = (t-48) >> 1; nt = (t-48) & 1; K = 512; N = 64;
    src = w2 + l*32768; dst = w2T + l*32768;
  }
  __shared__ float lds[32][33];
  int tx = threadIdx.x & 31, ty = threadIdx.x >> 5;
  int k0 = kt*32, n0 = nt*32;
  #pragma unroll
  for (int j=0;j<4;++j) lds[ty+8*j][tx] = src[(size_t)(k0+ty+8*j)*N + n0 + tx];
  __syncthreads();
  #pragma unroll
  for (int j=0;j<4;++j) {
    int nn = ty+8*j;
    dst[(size_t)(n0+nn)*K + k0 + tx] = f2bf(lds[tx][nn]);
  }
}

// ---------- building blocks ----------
DEV void make_frags_ln(const float* rowp, float mean, float inv,
    const float* __restrict__ s, const float* __restrict__ b, int kq,
    bf16x8& a0, bf16x8& a1){
  #pragma unroll
  for (int i=0;i<8;++i) a0[i] = f2bf((rowp[kq*8+i]-mean)*inv*s[kq*8+i]+b[kq*8+i]);
  #pragma unroll
  for (int i=0;i<8;++i) a1[i] = f2bf((rowp[32+kq*8+i]-mean)*inv*s[32+kq*8+i]+b[32+kq*8+i]);
}

// ---------- merged layer kernel v2: 1024 threads (16 waves), 64 rows/block ----------
// Same algorithm as r18; every phase's work split across 2x the waves.
template<bool EMBED, bool LAST>
__global__ __launch_bounds__(1024,1) void layer_kernel(
    const int* __restrict__ x, const float* __restrict__ emb,
    const unsigned short* __restrict__ qin, const unsigned short* __restrict__ kin,
    const unsigned short* __restrict__ vin,
    const short* __restrict__ woT, const float* __restrict__ bo,
    const float* __restrict__ ln2s, const float* __restrict__ ln2b,
    const short* __restrict__ w1T, const float* __restrict__ b1,
    const short* __restrict__ w2T, const float* __restrict__ b2,
    const float* __restrict__ lns, const float* __restrict__ lnb,   // LN1(next) or LNf
    const short* __restrict__ wqT, const short* __restrict__ wkT, const short* __restrict__ wvT,
    const float* __restrict__ bq, const float* __restrict__ bk, const float* __restrict__ bv,
    unsigned short* __restrict__ qo, unsigned short* __restrict__ ko, unsigned short* __restrict__ vo,
    float* __restrict__ h, float* __restrict__ part)
{
  __shared__ uint4 regA4[4608];   // 73728 B: Ks | (abL + hN + facc)
  __shared__ uint4 regB4[4688];   // 75008 B: Vs | mid
  __shared__ float mu[64], iv[64];

  unsigned short* Ks  = (unsigned short*)regA4;              // [576][64], swizzled
  unsigned short* abL = (unsigned short*)regA4;              // [64][72] bf16 (post-attn)
  float (*hN)[68]   = (float(*)[68])((char*)regA4 + 9216);
  float (*facc)[68] = (float(*)[68])((char*)regA4 + 26624);
  unsigned short* Vs = (unsigned short*)regB4;               // [64][VST] transposed
  short (*mid)[520]  = (short(*)[520])regB4;

  const int bid = blockIdx.x;
  const int row_g0 = bid * 64;
  const int tid = threadIdx.x;
  const int w = tid >> 6, lane = tid & 63;     // w = 0..15
  const int r = lane & 15, kq = lane >> 4;
  const int srow = tid >> 4, sd4 = tid & 15;   // stats/embed: 16 lanes/row, 4 elems each

  if constexpr (EMBED) {
    int tg = row_g0 + srow;
    int s = tg & (SB-1);
    int tok = x[tg];
    #pragma unroll
    for (int i=0;i<4;++i) {
      int d = sd4*4 + i;
      float fe = (float)(d & ~1) * (1.0f/64.0f);
      float invk = __expf(-9.210340371976184f * fe);
      float ang = (float)s * invk;
      float pe = (d & 1) ? __cosf(ang) : __sinf(ang);
      float val = emb[tok*DM + d] + pe;
      hN[srow][d] = val;
      h[(size_t)tg*DM + d] = val;
    }
  } else {
    const int bbase = row_g0 & ~(SB-1);     // batch base token index
    const int kwin0 = row_g0 - 256;         // global token index of staged key 0

    // ---- stage K [576][64] (swizzled) + V^T [64][VST]; grp-major = coalesced ----
    for (int idx = tid; idx < 4608; idx += 1024) {
      int e = idx >> 3, grp = idx & 7;
      int g = kwin0 + e;
      uint4 kv = make_uint4(0,0,0,0), vv = make_uint4(0,0,0,0);
      if ((unsigned)(g - bbase) < (unsigned)SB) {
        kv = *(const uint4*)(kin + (size_t)g*DM + grp*8);
        vv = *(const uint4*)(vin + (size_t)g*DM + grp*8);
      }
      *(uint4*)(Ks + e*64 + ((grp ^ (e & 7)) << 3)) = kv;
      const unsigned short* pv = (const unsigned short*)&vv;
      #pragma unroll
      for (int d = 0; d < 8; ++d) Vs[(grp*8 + d)*VST + e] = pv[d];
    }
    __syncthreads();

    // ---- attention: wave w -> head hh = w>>1, q-subtile qs = w&1 (one job/wave) ----
    const int qc = lane & 31;
    const int hf = lane >> 5;
    const int hh = w >> 1, qs = w & 1;

    f32x16 oacc = {};
    float lacc = 0.f;
    {
      const int qglob = row_g0 + qs*32 + qc;
      bf16x8 qfrag = {};
      if (hf == 0) qfrag = *(const bf16x8*)(qin + (size_t)qglob*DM + hh*8);
      for (int t = 0; t <= 16; ++t) {
        const int k0l = qs*32 + 32*t;
        const int k0g = kwin0 + k0l;
        if (k0g > bbase + SB-1 || k0g + 31 < bbase) continue;

        bf16x8 kfrag = {};
        if (hf == 0) {
          int e = k0l + qc;
          kfrag = *(const bf16x8*)(Ks + e*64 + ((hh ^ (e & 7)) << 3));
        }
        f32x16 s = __builtin_amdgcn_mfma_f32_32x32x16_bf16(kfrag, qfrag, (f32x16){}, 0, 0, 0);

        float pp[16];
        bool needmask = (t == 0) | (t == 16) | (k0g < bbase) | (k0g + 31 > bbase + SB-1);
        if (needmask) {
          #pragma unroll
          for (int rr = 0; rr < 16; ++rr) {
            int klg = k0g + (rr&3) + 8*(rr>>2) + 4*hf;
            bool ok = ((unsigned)(klg - qglob + 256) <= 512u) &&
                      ((unsigned)(klg - bbase) < (unsigned)SB);
            pp[rr] = ok ? __expf(s[rr]) : 0.f;
          }
        } else {
          #pragma unroll
          for (int rr = 0; rr < 16; ++rr) pp[rr] = __expf(s[rr]);
        }
        #pragma unroll
        for (int rr = 0; rr < 16; ++rr) lacc += pp[rr];

        unsigned pk[8];
        #pragma unroll
        for (int j = 0; j < 8; ++j) pk[j] = pack2bf(pp[2*j], pp[2*j+1]);
        unsigned sw[8];
        #pragma unroll
        for (int j = 0; j < 8; ++j) sw[j] = __shfl_xor(pk[j], 32, 64);

        union { unsigned u[4]; bf16x8 v; } pbA;
        pbA.u[0] = hf ? sw[2] : pk[0];
        pbA.u[1] = hf ? sw[3] : pk[1];
        pbA.u[2] = hf ? pk[2] : sw[0];
        pbA.u[3] = hf ? pk[3] : sw[1];
        bf16x8 va1 = {};
        if (qc < 8) va1 = *(const bf16x8*)(Vs + (hh*8 + qc)*VST + k0l + 8*hf);
        oacc = __builtin_amdgcn_mfma_f32_32x32x16_bf16(va1, pbA.v, oacc, 0, 0, 0);

        union { unsigned u[4]; bf16x8 v; } pbB;
        pbB.u[0] = hf ? sw[6] : pk[4];
        pbB.u[1] = hf ? sw[7] : pk[5];
        pbB.u[2] = hf ? pk[6] : sw[4];
        pbB.u[3] = hf ? pk[7] : sw[5];
        bf16x8 va2 = {};
        if (qc < 8) va2 = *(const bf16x8*)(Vs + (hh*8 + qc)*VST + k0l + 16 + 8*hf);
        oacc = __builtin_amdgcn_mfma_f32_32x32x16_bf16(va2, pbB.v, oacc, 0, 0, 0);
      }
    }
    float rcp = 1.f / (lacc + __shfl_xor(lacc, 32, 64));
    __syncthreads();    // all Ks/Vs reads complete

    // write attention output bf16 into abL (overlays Ks region)
    {
      unsigned short ov[4];
      #pragma unroll
      for (int j = 0; j < 4; ++j) ov[j] = (unsigned short)f2bf(oacc[j] * rcp);
      *(uint2*)(abL + (qs*32 + qc)*72 + hh*8 + 4*hf) = *(uint2*)ov;
    }
    __syncthreads();

    // ---- attn-out projection + residual: wave (rh = w>>2, ct = w&3): 16 rows x 16 cols ----
    {
      const int rh = w >> 2, ct = w & 3;
      const int col = ct*16 + r;
      const short* wp = woT + (size_t)col*64 + kq*8;
      bf16x8 wb0 = *(const bf16x8*)(wp);
      bf16x8 wb1 = *(const bf16x8*)(wp + 32);
      const short* abp = (const short*)(abL + (rh*16 + r)*72 + kq*8);
      bf16x8 a0 = *(const bf16x8*)abp;
      bf16x8 a1 = *(const bf16x8*)(abp + 32);
      f32x4 acc = (f32x4){0.f,0.f,0.f,0.f};
      acc = __builtin_amdgcn_mfma_f32_16x16x32_bf16(a0, wb0, acc, 0, 0, 0);
      acc = __builtin_amdgcn_mfma_f32_16x16x32_bf16(a1, wb1, acc, 0, 0, 0);
      #pragma unroll
      for (int j=0;j<4;++j) {
        int rl = rh*16 + kq*4 + j;
        hN[rl][col] = acc[j] + bo[col] + h[(size_t)(row_g0+rl)*DM + col];
      }
    }
  }
  __syncthreads();

  // LN stats (LN1 for EMBED, LN2 otherwise): 16 lanes/row
  {
    const float* p = &hN[srow][sd4*4];
    float v0=p[0], v1=p[1], v2=p[2], v3=p[3];
    float sum = v0+v1+v2+v3;
    sum += __shfl_xor(sum, 1, 64); sum += __shfl_xor(sum, 2, 64);
    sum += __shfl_xor(sum, 4, 64); sum += __shfl_xor(sum, 8, 64);
    float mean = sum * (1.f/64.f);
    float d0=v0-mean, d1=v1-mean, d2=v2-mean, d3=v3-mean;
    float sq = d0*d0+d1*d1+d2*d2+d3*d3;
    sq += __shfl_xor(sq, 1, 64); sq += __shfl_xor(sq, 2, 64);
    sq += __shfl_xor(sq, 4, 64); sq += __shfl_xor(sq, 8, 64);
    if (sd4 == 0) { mu[srow] = mean; iv[srow] = rsqrtf(sq*(1.f/64.f) + 1e-6f); }
  }
  __syncthreads();

  if constexpr (!EMBED) {
    // ---- fc1: wave w -> cols [32w, 32w+32), all 64 rows ----
    {
      bf16x8 a[4][2];
      #pragma unroll
      for (int rf=0; rf<4; ++rf)
        make_frags_ln(&hN[rf*16 + r][0], mu[rf*16 + r], iv[rf*16 + r], ln2s, ln2b, kq, a[rf][0], a[rf][1]);
      const int gc0 = w*32;
      bf16x8 wb[2][2];
      #pragma unroll
      for (int ct=0; ct<2; ++ct) {
        const short* wp = w1T + (size_t)(gc0 + ct*16 + r)*64 + kq*8;
        wb[ct][0] = *(const bf16x8*)(wp);
        wb[ct][1] = *(const bf16x8*)(wp + 32);
      }
      f32x4 acc1[2][4];
      #pragma unroll
      for (int ct=0;ct<2;++ct)
        #pragma unroll
        for (int rf=0;rf<4;++rf) acc1[ct][rf] = (f32x4){0.f,0.f,0.f,0.f};
      #pragma unroll
      for (int ct=0; ct<2; ++ct)
        #pragma unroll
        for (int rf=0; rf<4; ++rf) {
          acc1[ct][rf] = __builtin_amdgcn_mfma_f32_16x16x32_bf16(a[rf][0], wb[ct][0], acc1[ct][rf], 0, 0, 0);
          acc1[ct][rf] = __builtin_amdgcn_mfma_f32_16x16x32_bf16(a[rf][1], wb[ct][1], acc1[ct][rf], 0, 0, 0);
        }
      __syncthreads();   // Vs region free before mid writes
      #pragma unroll
      for (int ct=0; ct<2; ++ct) {
        int gcol = gc0 + ct*16 + r;
        float bb = b1[gcol];
        #pragma unroll
        for (int rf=0; rf<4; ++rf)
          #pragma unroll
          for (int j=0; j<4; ++j)
            mid[rf*16 + kq*4 + j][gcol] = f2bf(gelu_fast(acc1[ct][rf][j] + bb));
      }
    }
    __syncthreads();

    // ---- fc2: wave (kh = w>>3, rh2 = (w>>2)&1, ct2 = w&3): 32 rows x 16 cols, K-half ----
    {
      const int kh = w >> 3, rh2 = (w >> 2) & 1, ct2 = w & 3;
      const int col2 = ct2*16 + r;
      const int rbase = rh2*32;
      bf16x8 wf[8];
      #pragma unroll
      for (int ks=0; ks<8; ++ks)
        wf[ks] = *(const bf16x8*)(w2T + (size_t)col2*512 + kh*256 + ks*32 + kq*8);
      f32x4 acc2[2];
      #pragma unroll
      for (int rf=0;rf<2;++rf) acc2[rf] = (f32x4){0.f,0.f,0.f,0.f};
      #pragma unroll
      for (int ks=0; ks<8; ++ks)
        #pragma unroll
        for (int rf=0; rf<2; ++rf) {
          bf16x8 af = *(const bf16x8*)(&mid[rbase + rf*16 + r][kh*256 + ks*32 + kq*8]);
          acc2[rf] = __builtin_amdgcn_mfma_f32_16x16x32_bf16(af, wf[ks], acc2[rf], 0, 0, 0);
        }
      if (kh == 0) {
        #pragma unroll
        for (int rf=0; rf<2; ++rf)
          #pragma unroll
          for (int j=0;j<4;++j)
            facc[rbase + rf*16 + kq*4 + j][col2] = acc2[rf][j];
      }
      __syncthreads();
      if (kh == 1) {
        float bb = b2[col2];
        #pragma unroll
        for (int rf=0; rf<2; ++rf)
          #pragma unroll
          for (int j=0;j<4;++j) {
            int rl = rbase + rf*16 + kq*4 + j;
            float val = acc2[rf][j] + facc[rl][col2] + bb + hN[rl][col2];
            hN[rl][col2] = val;
            h[(size_t)(row_g0+rl)*DM + col2] = val;
          }
      }
    }
    __syncthreads();

    // LN stats for LN1(next) / LNf
    {
      const float* p = &hN[srow][sd4*4];
      float v0=p[0], v1=p[1], v2=p[2], v3=p[3];
      float sum = v0+v1+v2+v3;
      sum += __shfl_xor(sum, 1, 64); sum += __shfl_xor(sum, 2, 64);
      sum += __shfl_xor(sum, 4, 64); sum += __shfl_xor(sum, 8, 64);
      float mean = sum * (1.f/64.f);
      float d0=v0-mean, d1=v1-mean, d2=v2-mean, d3=v3-mean;
      float sq = d0*d0+d1*d1+d2*d2+d3*d3;
      sq += __shfl_xor(sq, 1, 64); sq += __shfl_xor(sq, 2, 64);
      sq += __shfl_xor(sq, 4, 64); sq += __shfl_xor(sq, 8, 64);
      if (sd4 == 0) { mu[srow] = mean; iv[srow] = rsqrtf(sq*(1.f/64.f) + 1e-6f); }
    }
    __syncthreads();
  }

  if constexpr (!LAST) {
    // qkv of (next) layer: 12 jobs; wave w does job w (w<12)
    const float qscale = 0.35355339059327373f;
    if (w < 12) {
      bf16x8 a[4][2];
      #pragma unroll
      for (int rf=0; rf<4; ++rf)
        make_frags_ln(&hN[rf*16 + r][0], mu[rf*16 + r], iv[rf*16 + r], lns, lnb, kq, a[rf][0], a[rf][1]);
      int m = w >> 2, ct = w & 3;
      const short* WT = m==0 ? wqT : (m==1 ? wkT : wvT);
      int col = ct*16 + r;
      const short* wp = WT + (size_t)col*64 + kq*8;
      bf16x8 wb0 = *(const bf16x8*)(wp);
      bf16x8 wb1 = *(const bf16x8*)(wp + 32);
      float bias = (m==0 ? bq : (m==1 ? bk : bv))[col];
      float scale = (m==0) ? qscale : 1.f;
      unsigned short* OPT = m==0 ? qo : (m==1 ? ko : vo);
      #pragma unroll
      for (int rf=0; rf<4; ++rf) {
        f32x4 acc = (f32x4){0.f,0.f,0.f,0.f};
        acc = __builtin_amdgcn_mfma_f32_16x16x32_bf16(a[rf][0], wb0, acc, 0, 0, 0);
        acc = __builtin_amdgcn_mfma_f32_16x16x32_bf16(a[rf][1], wb1, acc, 0, 0, 0);
        #pragma unroll
        for (int j=0;j<4;++j) {
          size_t oi = (size_t)(row_g0 + rf*16 + kq*4 + j)*DM + col;
          OPT[oi] = (unsigned short)f2bf((acc[j] + bias)*scale);
        }
      }
    }
  } else {
    // final LN in place + pool partial (64 rows)
    float mean = mu[srow], inv = iv[srow];
    #pragma unroll
    for (int i=0;i<4;++i) {
      int d = sd4*4 + i;
      hN[srow][d] = (hN[srow][d]-mean)*inv*lns[d] + lnb[d];
    }
    __syncthreads();
    if (tid < 64) {
      float s = 0.f;
      #pragma unroll 4
      for (int rr=0; rr<64; ++rr) s += hN[rr][tid];
      part[bid*64 + tid] = s;
    }
  }
}

// ---------- pool finalize + classifier ----------
__global__ __launch_bounds__(256) void pool_finalize(const float* __restrict__ part,
    const float* __restrict__ wcls, const float* __restrict__ bcls, float* __restrict__ out)
{
  int tid = threadIdx.x;
  int b = tid >> 6, d = tid & 63;
  float sum = 0.f;
  #pragma unroll 8
  for (int i = 0; i < 64; ++i) sum += part[(b*64 + i)*64 + d];
  __shared__ float pooled[4][64];
  pooled[b][d] = sum * (1.f/4096.f);
  __syncthreads();
  if (tid < 40) {
    int bb = tid / 10, c = tid % 10;
    float acc = bcls[c];
    #pragma unroll
    for (int dd = 0; dd < 64; ++dd) acc = fmaf(pooled[bb][dd], wcls[dd*10 + c], acc);
    out[tid] = acc;
  }
}

// ---------- launcher ----------
extern "C" void kernel_launch(void* const* d_in, const int* in_sizes, int n_in,
                              void* d_out, int out_size, void* d_ws, size_t ws_size,
                              hipStream_t stream)
{
  const int*   x    = (const int*)d_in[0];
  const float* emb  = (const float*)d_in[1];
  const float* wq   = (const float*)d_in[2];
  const float* bq   = (const float*)d_in[3];
  const float* wk   = (const float*)d_in[4];
  const float* bk   = (const float*)d_in[5];
  const float* wv   = (const float*)d_in[6];
  const float* bv   = (const float*)d_in[7];
  const float* wo   = (const float*)d_in[8];
  const float* bo   = (const float*)d_in[9];
  const float* ln1s = (const float*)d_in[10];
  const float* ln1b = (const float*)d_in[11];
  const float* ln2s = (const float*)d_in[12];
  const float* ln2b = (const float*)d_in[13];
  const float* w1   = (const float*)d_in[14];
  const float* b1   = (const float*)d_in[15];
  const float* w2   = (const float*)d_in[16];
  const float* b2   = (const float*)d_in[17];
  const float* lnfs = (const float*)d_in[18];
  const float* lnfb = (const float*)d_in[19];
  const float* wcls = (const float*)d_in[20];
  const float* bcls = (const float*)d_in[21];
  float* out = (float*)d_out;

  char* wsb = (char*)d_ws;
  const size_t MB = 1u << 20;
  float* h  = (float*)(wsb);                               // 4 MB f32 [16384][64]
  unsigned short* qA = (unsigned short*)(wsb + 4*MB);      // ping-pong qkv (2 MB each)
  unsigned short* kA = (unsigned short*)(wsb + 6*MB);
  unsigned short* vA = (unsigned short*)(wsb + 8*MB);
  unsigned short* qB = (unsigned short*)(wsb + 10*MB);
  unsigned short* kB = (unsigned short*)(wsb + 12*MB);
  unsigned short* vB = (unsigned short*)(wsb + 14*MB);
  short* wqT = (short*)(wsb + 16*MB);
  short* wkT = (short*)(wsb + 16*MB + 32*1024);
  short* wvT = (short*)(wsb + 16*MB + 64*1024);
  short* woT = (short*)(wsb + 16*MB + 96*1024);
  short* w1T = (short*)(wsb + 16*MB + 128*1024);           // 256 KB
  short* w2T = (short*)(wsb + 16*MB + 384*1024);           // 256 KB
  float* part = (float*)(wsb + 17*MB);                     // 64 KB

  wconv<<<dim3(80,4),256,0,stream>>>(wq,wk,wv,wo,w1,w2, wqT,wkT,wvT,woT,w1T,w2T);

  // head: embed + LN1(l0) + qkv(l0) -> A
  layer_kernel<true,false><<<256,1024,0,stream>>>(
      x, emb, nullptr, nullptr, nullptr,
      nullptr, nullptr, nullptr, nullptr,
      nullptr, nullptr, nullptr, nullptr,
      ln1s, ln1b,
      wqT, wkT, wvT, bq, bk, bv,
      qA, kA, vA, h, nullptr);

  for (int l = 0; l < 4; ++l) {
    unsigned short* qi = (l & 1) ? qB : qA;
    unsigned short* ki = (l & 1) ? kB : kA;
    unsigned short* vi = (l & 1) ? vB : vA;
    unsigned short* qu = (l & 1) ? qA : qB;
    unsigned short* ku = (l & 1) ? kA : kB;
    unsigned short* vu = (l & 1) ? vA : vB;
    if (l < 3) {
      layer_kernel<false,false><<<256,1024,0,stream>>>(
          nullptr, nullptr, qi, ki, vi,
          woT+4096*l, bo+64*l, ln2s+64*l, ln2b+64*l,
          w1T+32768*l, b1+512*l, w2T+32768*l, b2+64*l,
          ln1s+64*(l+1), ln1b+64*(l+1),
          wqT+4096*(l+1), wkT+4096*(l+1), wvT+4096*(l+1),
          bq+64*(l+1), bk+64*(l+1), bv+64*(l+1),
          qu, ku, vu, h, nullptr);
    } else {
      layer_kernel<false,true><<<256,1024,0,stream>>>(
          nullptr, nullptr, qi, ki, vi,
          woT+4096*l, bo+64*l, ln2s+64*l, ln2b+64*l,
          w1T+32768*l, b1+512*l, w2T+32768*l, b2+64*l,
          lnfs, lnfb,
          nullptr, nullptr, nullptr, nullptr, nullptr, nullptr,
          nullptr, nullptr, nullptr, h, part);
    }
  }
  pool_finalize<<<1,256,0,stream>>>(part, wcls, bcls, out);
}

// Round 21
// 167.042 us; speedup vs baseline: 1.2384x; 1.0928x over previous
//
#include <hip/hip_runtime.h>
#include <hip/hip_bf16.h>

#define DEV __device__ __forceinline__

typedef __attribute__((ext_vector_type(8))) short bf16x8;
typedef __attribute__((ext_vector_type(4))) float f32x4;
typedef __attribute__((ext_vector_type(16))) float f32x16;

// ---------- helpers ----------
DEV short f2bf(float x){ __hip_bfloat16 h = __float2bfloat16(x); return *(short*)&h; }
DEV unsigned pack2bf(float a, float b){
  return (unsigned)(unsigned short)f2bf(a) | ((unsigned)(unsigned short)f2bf(b) << 16);
}
DEV float fexp2(float x){ return __builtin_amdgcn_exp2f(x); }   // v_exp_f32
// gelu(x) = x * sigmoid(2z), z = 0.79788456(x + 0.044715x^3); exp folded to exp2, div -> rcp
DEV float gelu_fast(float x){
  float u = x + 0.044715f*x*x*x;
  float t = fexp2(-2.3022082f*u);
  return x * __builtin_amdgcn_rcpf(1.f + t);
}

#define SB 4096
#define NT 16384
#define DM 64
#define VST 586   // Vs row stride (ushorts); 293 dwords == 5 mod 32 -> writes 2-way, reads conflict-free

// ---------- weight convert+transpose: f32 [K][N] -> bf16 [N][K], 32x32 tiles ----------
__global__ __launch_bounds__(256) void wconv(
    const float* __restrict__ wq, const float* __restrict__ wk,
    const float* __restrict__ wv, const float* __restrict__ wo,
    const float* __restrict__ w1, const float* __restrict__ w2,
    short* __restrict__ wqT, short* __restrict__ wkT,
    short* __restrict__ wvT, short* __restrict__ woT,
    short* __restrict__ w1T, short* __restrict__ w2T)
{
  int t = blockIdx.x, l = blockIdx.y;
  const float* src; short* dst; int K, N, kt, nt;
  if (t < 16) {
    int m = t >> 2, sub = t & 3; kt = sub >> 1; nt = sub & 1; K = 64; N = 64;
    const float* s4[4] = {wq, wk, wv, wo};
    short*       d4[4] = {wqT, wkT, wvT, woT};
    src = s4[m] + l*4096; dst = d4[m] + l*4096;
  } else if (t < 48) {
    kt = (t-16) >> 4; nt = (t-16) & 15; K = 64; N = 512;
    src = w1 + l*32768; dst = w1T + l*32768;
  } else {
    kt = (t-48) >> 1; nt = (t-48) & 1; K = 512; N = 64;
    src = w2 + l*32768; dst = w2T + l*32768;
  }
  __shared__ float lds[32][33];
  int tx = threadIdx.x & 31, ty = threadIdx.x >> 5;
  int k0 = kt*32, n0 = nt*32;
  #pragma unroll
  for (int j=0;j<4;++j) lds[ty+8*j][tx] = src[(size_t)(k0+ty+8*j)*N + n0 + tx];
  __syncthreads();
  #pragma unroll
  for (int j=0;j<4;++j) {
    int nn = ty+8*j;
    dst[(size_t)(n0+nn)*K + k0 + tx] = f2bf(lds[tx][nn]);
  }
}

// ---------- merged layer kernel v3: 1024 threads (16 waves), 64 rows/block ----------
// LN'd activations materialized ONCE into LDS hB (bf16); fc1/qkv read A-frags via LDS.
// Q pre-scaled by 1/sqrt(8)*log2(e) -> attention softmax uses exp2 (exact).
template<bool EMBED, bool LAST>
__global__ __launch_bounds__(1024,1) void layer_kernel(
    const int* __restrict__ x, const float* __restrict__ emb,
    const unsigned short* __restrict__ qin, const unsigned short* __restrict__ kin,
    const unsigned short* __restrict__ vin,
    const short* __restrict__ woT, const float* __restrict__ bo,
    const float* __restrict__ ln2s, const float* __restrict__ ln2b,
    const short* __restrict__ w1T, const float* __restrict__ b1,
    const short* __restrict__ w2T, const float* __restrict__ b2,
    const float* __restrict__ lns, const float* __restrict__ lnb,   // LN1(next) or LNf
    const short* __restrict__ wqT, const short* __restrict__ wkT, const short* __restrict__ wvT,
    const float* __restrict__ bq, const float* __restrict__ bk, const float* __restrict__ bv,
    unsigned short* __restrict__ qo, unsigned short* __restrict__ ko, unsigned short* __restrict__ vo,
    float* __restrict__ h, float* __restrict__ part)
{
  __shared__ uint4 regA4[4608];   // 73728 B: Ks | (abL + hN + facc + hB)
  __shared__ uint4 regB4[4688];   // 75008 B: Vs | mid
  __shared__ float mu[64], iv[64];

  unsigned short* Ks  = (unsigned short*)regA4;              // [576][64], swizzled
  unsigned short* abL = (unsigned short*)regA4;              // [64][72] bf16 (post-attn)
  float (*hN)[68]   = (float(*)[68])((char*)regA4 + 9216);
  float (*facc)[68] = (float(*)[68])((char*)regA4 + 26624);
  unsigned short* hB = (unsigned short*)((char*)regA4 + 44032);  // [64][72] bf16 LN'd
  unsigned short* Vs = (unsigned short*)regB4;               // [64][VST] transposed
  short (*mid)[520]  = (short(*)[520])regB4;

  const int bid = blockIdx.x;
  const int row_g0 = bid * 64;
  const int tid = threadIdx.x;
  const int w = tid >> 6, lane = tid & 63;     // w = 0..15
  const int r = lane & 15, kq = lane >> 4;
  const int srow = tid >> 4, sd4 = tid & 15;   // stats/embed: 16 lanes/row, 4 elems each

  if constexpr (EMBED) {
    int tg = row_g0 + srow;
    int s = tg & (SB-1);
    int tok = x[tg];
    #pragma unroll
    for (int i=0;i<4;++i) {
      int d = sd4*4 + i;
      float fe = (float)(d & ~1) * (1.0f/64.0f);
      float invk = __expf(-9.210340371976184f * fe);
      float ang = (float)s * invk;
      float pe = (d & 1) ? __cosf(ang) : __sinf(ang);
      float val = emb[tok*DM + d] + pe;
      hN[srow][d] = val;
      h[(size_t)tg*DM + d] = val;
    }
  } else {
    const int bbase = row_g0 & ~(SB-1);     // batch base token index
    const int kwin0 = row_g0 - 256;         // global token index of staged key 0

    // ---- stage K [576][64] (swizzled) + V^T [64][VST]; grp-major = coalesced ----
    for (int idx = tid; idx < 4608; idx += 1024) {
      int e = idx >> 3, grp = idx & 7;
      int g = kwin0 + e;
      uint4 kv = make_uint4(0,0,0,0), vv = make_uint4(0,0,0,0);
      if ((unsigned)(g - bbase) < (unsigned)SB) {
        kv = *(const uint4*)(kin + (size_t)g*DM + grp*8);
        vv = *(const uint4*)(vin + (size_t)g*DM + grp*8);
      }
      *(uint4*)(Ks + e*64 + ((grp ^ (e & 7)) << 3)) = kv;
      const unsigned short* pv = (const unsigned short*)&vv;
      #pragma unroll
      for (int d = 0; d < 8; ++d) Vs[(grp*8 + d)*VST + e] = pv[d];
    }
    __syncthreads();

    // ---- attention: wave w -> head hh = w>>1, q-subtile qs = w&1 (one job/wave) ----
    const int qc = lane & 31;
    const int hf = lane >> 5;
    const int hh = w >> 1, qs = w & 1;

    f32x16 oacc = {};
    float lacc = 0.f;
    {
      const int qglob = row_g0 + qs*32 + qc;
      bf16x8 qfrag = {};
      if (hf == 0) qfrag = *(const bf16x8*)(qin + (size_t)qglob*DM + hh*8);
      for (int t = 0; t <= 16; ++t) {
        const int k0l = qs*32 + 32*t;
        const int k0g = kwin0 + k0l;
        if (k0g > bbase + SB-1 || k0g + 31 < bbase) continue;

        bf16x8 kfrag = {};
        if (hf == 0) {
          int e = k0l + qc;
          kfrag = *(const bf16x8*)(Ks + e*64 + ((hh ^ (e & 7)) << 3));
        }
        f32x16 s = __builtin_amdgcn_mfma_f32_32x32x16_bf16(kfrag, qfrag, (f32x16){}, 0, 0, 0);

        float pp[16];
        bool needmask = (t == 0) | (t == 16) | (k0g < bbase) | (k0g + 31 > bbase + SB-1);
        if (needmask) {
          #pragma unroll
          for (int rr = 0; rr < 16; ++rr) {
            int klg = k0g + (rr&3) + 8*(rr>>2) + 4*hf;
            bool ok = ((unsigned)(klg - qglob + 256) <= 512u) &&
                      ((unsigned)(klg - bbase) < (unsigned)SB);
            pp[rr] = ok ? fexp2(s[rr]) : 0.f;
          }
        } else {
          #pragma unroll
          for (int rr = 0; rr < 16; ++rr) pp[rr] = fexp2(s[rr]);
        }
        #pragma unroll
        for (int rr = 0; rr < 16; ++rr) lacc += pp[rr];

        unsigned pk[8];
        #pragma unroll
        for (int j = 0; j < 8; ++j) pk[j] = pack2bf(pp[2*j], pp[2*j+1]);
        unsigned sw[8];
        #pragma unroll
        for (int j = 0; j < 8; ++j) sw[j] = __shfl_xor(pk[j], 32, 64);

        union { unsigned u[4]; bf16x8 v; } pbA;
        pbA.u[0] = hf ? sw[2] : pk[0];
        pbA.u[1] = hf ? sw[3] : pk[1];
        pbA.u[2] = hf ? pk[2] : sw[0];
        pbA.u[3] = hf ? pk[3] : sw[1];
        bf16x8 va1 = {};
        if (qc < 8) va1 = *(const bf16x8*)(Vs + (hh*8 + qc)*VST + k0l + 8*hf);
        oacc = __builtin_amdgcn_mfma_f32_32x32x16_bf16(va1, pbA.v, oacc, 0, 0, 0);

        union { unsigned u[4]; bf16x8 v; } pbB;
        pbB.u[0] = hf ? sw[6] : pk[4];
        pbB.u[1] = hf ? sw[7] : pk[5];
        pbB.u[2] = hf ? pk[6] : sw[4];
        pbB.u[3] = hf ? pk[7] : sw[5];
        bf16x8 va2 = {};
        if (qc < 8) va2 = *(const bf16x8*)(Vs + (hh*8 + qc)*VST + k0l + 16 + 8*hf);
        oacc = __builtin_amdgcn_mfma_f32_32x32x16_bf16(va2, pbB.v, oacc, 0, 0, 0);
      }
    }
    float rcp = 1.f / (lacc + __shfl_xor(lacc, 32, 64));
    __syncthreads();    // all Ks/Vs reads complete

    // write attention output bf16 into abL (overlays Ks region)
    {
      unsigned short ov[4];
      #pragma unroll
      for (int j = 0; j < 4; ++j) ov[j] = (unsigned short)f2bf(oacc[j] * rcp);
      *(uint2*)(abL + (qs*32 + qc)*72 + hh*8 + 4*hf) = *(uint2*)ov;
    }
    __syncthreads();

    // ---- attn-out projection + residual: wave (rh = w>>2, ct = w&3): 16 rows x 16 cols ----
    {
      const int rh = w >> 2, ct = w & 3;
      const int col = ct*16 + r;
      const short* wp = woT + (size_t)col*64 + kq*8;
      bf16x8 wb0 = *(const bf16x8*)(wp);
      bf16x8 wb1 = *(const bf16x8*)(wp + 32);
      const short* abp = (const short*)(abL + (rh*16 + r)*72 + kq*8);
      bf16x8 a0 = *(const bf16x8*)abp;
      bf16x8 a1 = *(const bf16x8*)(abp + 32);
      f32x4 acc = (f32x4){0.f,0.f,0.f,0.f};
      acc = __builtin_amdgcn_mfma_f32_16x16x32_bf16(a0, wb0, acc, 0, 0, 0);
      acc = __builtin_amdgcn_mfma_f32_16x16x32_bf16(a1, wb1, acc, 0, 0, 0);
      #pragma unroll
      for (int j=0;j<4;++j) {
        int rl = rh*16 + kq*4 + j;
        hN[rl][col] = acc[j] + bo[col] + h[(size_t)(row_g0+rl)*DM + col];
      }
    }
  }
  __syncthreads();

  // LN stats (LN1 for EMBED, LN2 otherwise): 16 lanes/row
  {
    const float* p = &hN[srow][sd4*4];
    float v0=p[0], v1=p[1], v2=p[2], v3=p[3];
    float sum = v0+v1+v2+v3;
    sum += __shfl_xor(sum, 1, 64); sum += __shfl_xor(sum, 2, 64);
    sum += __shfl_xor(sum, 4, 64); sum += __shfl_xor(sum, 8, 64);
    float mean = sum * (1.f/64.f);
    float d0=v0-mean, d1=v1-mean, d2=v2-mean, d3=v3-mean;
    float sq = d0*d0+d1*d1+d2*d2+d3*d3;
    sq += __shfl_xor(sq, 1, 64); sq += __shfl_xor(sq, 2, 64);
    sq += __shfl_xor(sq, 4, 64); sq += __shfl_xor(sq, 8, 64);
    if (sd4 == 0) { mu[srow] = mean; iv[srow] = rsqrtf(sq*(1.f/64.f) + 1e-6f); }
  }
  __syncthreads();

  // LN apply -> hB bf16 (ONCE; consumed as MFMA A-frags by fc1 / qkv)
  {
    const float* sS; const float* sBv;
    if constexpr (EMBED) { sS = lns; sBv = lnb; } else { sS = ln2s; sBv = ln2b; }
    float mean = mu[srow], inv = iv[srow];
    #pragma unroll
    for (int i=0;i<4;++i) {
      int d = sd4*4 + i;
      hB[srow*72 + d] = (unsigned short)f2bf((hN[srow][d]-mean)*inv*sS[d] + sBv[d]);
    }
  }
  __syncthreads();

  if constexpr (!EMBED) {
    // ---- fc1: wave w -> cols [32w, 32w+32), all 64 rows; A-frags from hB ----
    {
      bf16x8 a[4][2];
      #pragma unroll
      for (int rf=0; rf<4; ++rf) {
        const unsigned short* hp = hB + (rf*16 + r)*72 + kq*8;
        a[rf][0] = *(const bf16x8*)(hp);
        a[rf][1] = *(const bf16x8*)(hp + 32);
      }
      const int gc0 = w*32;
      bf16x8 wb[2][2];
      #pragma unroll
      for (int ct=0; ct<2; ++ct) {
        const short* wp = w1T + (size_t)(gc0 + ct*16 + r)*64 + kq*8;
        wb[ct][0] = *(const bf16x8*)(wp);
        wb[ct][1] = *(const bf16x8*)(wp + 32);
      }
      f32x4 acc1[2][4];
      #pragma unroll
      for (int ct=0;ct<2;++ct)
        #pragma unroll
        for (int rf=0;rf<4;++rf) acc1[ct][rf] = (f32x4){0.f,0.f,0.f,0.f};
      #pragma unroll
      for (int ct=0; ct<2; ++ct)
        #pragma unroll
        for (int rf=0; rf<4; ++rf) {
          acc1[ct][rf] = __builtin_amdgcn_mfma_f32_16x16x32_bf16(a[rf][0], wb[ct][0], acc1[ct][rf], 0, 0, 0);
          acc1[ct][rf] = __builtin_amdgcn_mfma_f32_16x16x32_bf16(a[rf][1], wb[ct][1], acc1[ct][rf], 0, 0, 0);
        }
      __syncthreads();   // Vs region free before mid writes
      #pragma unroll
      for (int ct=0; ct<2; ++ct) {
        int gcol = gc0 + ct*16 + r;
        float bb = b1[gcol];
        #pragma unroll
        for (int rf=0; rf<4; ++rf)
          #pragma unroll
          for (int j=0; j<4; ++j)
            mid[rf*16 + kq*4 + j][gcol] = f2bf(gelu_fast(acc1[ct][rf][j] + bb));
      }
    }
    __syncthreads();

    // ---- fc2: wave (kh = w>>3, rh2 = (w>>2)&1, ct2 = w&3): 32 rows x 16 cols, K-half ----
    {
      const int kh = w >> 3, rh2 = (w >> 2) & 1, ct2 = w & 3;
      const int col2 = ct2*16 + r;
      const int rbase = rh2*32;
      bf16x8 wf[8];
      #pragma unroll
      for (int ks=0; ks<8; ++ks)
        wf[ks] = *(const bf16x8*)(w2T + (size_t)col2*512 + kh*256 + ks*32 + kq*8);
      f32x4 acc2[2];
      #pragma unroll
      for (int rf=0;rf<2;++rf) acc2[rf] = (f32x4){0.f,0.f,0.f,0.f};
      #pragma unroll
      for (int ks=0; ks<8; ++ks)
        #pragma unroll
        for (int rf=0; rf<2; ++rf) {
          bf16x8 af = *(const bf16x8*)(&mid[rbase + rf*16 + r][kh*256 + ks*32 + kq*8]);
          acc2[rf] = __builtin_amdgcn_mfma_f32_16x16x32_bf16(af, wf[ks], acc2[rf], 0, 0, 0);
        }
      if (kh == 0) {
        #pragma unroll
        for (int rf=0; rf<2; ++rf)
          #pragma unroll
          for (int j=0;j<4;++j)
            facc[rbase + rf*16 + kq*4 + j][col2] = acc2[rf][j];
      }
      __syncthreads();
      if (kh == 1) {
        float bb = b2[col2];
        #pragma unroll
        for (int rf=0; rf<2; ++rf)
          #pragma unroll
          for (int j=0;j<4;++j) {
            int rl = rbase + rf*16 + kq*4 + j;
            float val = acc2[rf][j] + facc[rl][col2] + bb + hN[rl][col2];
            hN[rl][col2] = val;
            h[(size_t)(row_g0+rl)*DM + col2] = val;
          }
      }
    }
    __syncthreads();

    // LN stats for LN1(next) / LNf
    {
      const float* p = &hN[srow][sd4*4];
      float v0=p[0], v1=p[1], v2=p[2], v3=p[3];
      float sum = v0+v1+v2+v3;
      sum += __shfl_xor(sum, 1, 64); sum += __shfl_xor(sum, 2, 64);
      sum += __shfl_xor(sum, 4, 64); sum += __shfl_xor(sum, 8, 64);
      float mean = sum * (1.f/64.f);
      float d0=v0-mean, d1=v1-mean, d2=v2-mean, d3=v3-mean;
      float sq = d0*d0+d1*d1+d2*d2+d3*d3;
      sq += __shfl_xor(sq, 1, 64); sq += __shfl_xor(sq, 2, 64);
      sq += __shfl_xor(sq, 4, 64); sq += __shfl_xor(sq, 8, 64);
      if (sd4 == 0) { mu[srow] = mean; iv[srow] = rsqrtf(sq*(1.f/64.f) + 1e-6f); }
    }
    __syncthreads();
  }

  if constexpr (!LAST) {
    if constexpr (!EMBED) {
      // LN1(next) apply -> hB (EMBED already wrote hB with lns/lnb)
      float mean = mu[srow], inv = iv[srow];
      #pragma unroll
      for (int i=0;i<4;++i) {
        int d = sd4*4 + i;
        hB[srow*72 + d] = (unsigned short)f2bf((hN[srow][d]-mean)*inv*lns[d] + lnb[d]);
      }
      __syncthreads();
    }
    // qkv of (next) layer: 12 jobs; wave w does job w (w<12); A-frags from hB
    // qscale folds 1/sqrt(8) * log2(e) so attention can use exp2 directly.
    const float qscale = 0.51006977f;
    if (w < 12) {
      bf16x8 a[4][2];
      #pragma unroll
      for (int rf=0; rf<4; ++rf) {
        const unsigned short* hp = hB + (rf*16 + r)*72 + kq*8;
        a[rf][0] = *(const bf16x8*)(hp);
        a[rf][1] = *(const bf16x8*)(hp + 32);
      }
      int m = w >> 2, ct = w & 3;
      const short* WT = m==0 ? wqT : (m==1 ? wkT : wvT);
      int col = ct*16 + r;
      const short* wp = WT + (size_t)col*64 + kq*8;
      bf16x8 wb0 = *(const bf16x8*)(wp);
      bf16x8 wb1 = *(const bf16x8*)(wp + 32);
      float bias = (m==0 ? bq : (m==1 ? bk : bv))[col];
      float scale = (m==0) ? qscale : 1.f;
      unsigned short* OPT = m==0 ? qo : (m==1 ? ko : vo);
      #pragma unroll
      for (int rf=0; rf<4; ++rf) {
        f32x4 acc = (f32x4){0.f,0.f,0.f,0.f};
        acc = __builtin_amdgcn_mfma_f32_16x16x32_bf16(a[rf][0], wb0, acc, 0, 0, 0);
        acc = __builtin_amdgcn_mfma_f32_16x16x32_bf16(a[rf][1], wb1, acc, 0, 0, 0);
        #pragma unroll
        for (int j=0;j<4;++j) {
          size_t oi = (size_t)(row_g0 + rf*16 + kq*4 + j)*DM + col;
          OPT[oi] = (unsigned short)f2bf((acc[j] + bias)*scale);
        }
      }
    }
  } else {
    // final LN in place + pool partial (64 rows)
    float mean = mu[srow], inv = iv[srow];
    #pragma unroll
    for (int i=0;i<4;++i) {
      int d = sd4*4 + i;
      hN[srow][d] = (hN[srow][d]-mean)*inv*lns[d] + lnb[d];
    }
    __syncthreads();
    if (tid < 64) {
      float s = 0.f;
      #pragma unroll 4
      for (int rr=0; rr<64; ++rr) s += hN[rr][tid];
      part[bid*64 + tid] = s;
    }
  }
}

// ---------- pool finalize + classifier ----------
__global__ __launch_bounds__(256) void pool_finalize(const float* __restrict__ part,
    const float* __restrict__ wcls, const float* __restrict__ bcls, float* __restrict__ out)
{
  int tid = threadIdx.x;
  int b = tid >> 6, d = tid & 63;
  float sum = 0.f;
  #pragma unroll 8
  for (int i = 0; i < 64; ++i) sum += part[(b*64 + i)*64 + d];
  __shared__ float pooled[4][64];
  pooled[b][d] = sum * (1.f/4096.f);
  __syncthreads();
  if (tid < 40) {
    int bb = tid / 10, c = tid % 10;
    float acc = bcls[c];
    #pragma unroll
    for (int dd = 0; dd < 64; ++dd) acc = fmaf(pooled[bb][dd], wcls[dd*10 + c], acc);
    out[tid] = acc;
  }
}

// ---------- launcher ----------
extern "C" void kernel_launch(void* const* d_in, const int* in_sizes, int n_in,
                              void* d_out, int out_size, void* d_ws, size_t ws_size,
                              hipStream_t stream)
{
  const int*   x    = (const int*)d_in[0];
  const float* emb  = (const float*)d_in[1];
  const float* wq   = (const float*)d_in[2];
  const float* bq   = (const float*)d_in[3];
  const float* wk   = (const float*)d_in[4];
  const float* bk   = (const float*)d_in[5];
  const float* wv   = (const float*)d_in[6];
  const float* bv   = (const float*)d_in[7];
  const float* wo   = (const float*)d_in[8];
  const float* bo   = (const float*)d_in[9];
  const float* ln1s = (const float*)d_in[10];
  const float* ln1b = (const float*)d_in[11];
  const float* ln2s = (const float*)d_in[12];
  const float* ln2b = (const float*)d_in[13];
  const float* w1   = (const float*)d_in[14];
  const float* b1   = (const float*)d_in[15];
  const float* w2   = (const float*)d_in[16];
  const float* b2   = (const float*)d_in[17];
  const float* lnfs = (const float*)d_in[18];
  const float* lnfb = (const float*)d_in[19];
  const float* wcls = (const float*)d_in[20];
  const float* bcls = (const float*)d_in[21];
  float* out = (float*)d_out;

  char* wsb = (char*)d_ws;
  const size_t MB = 1u << 20;
  float* h  = (float*)(wsb);                               // 4 MB f32 [16384][64]
  unsigned short* qA = (unsigned short*)(wsb + 4*MB);      // ping-pong qkv (2 MB each)
  unsigned short* kA = (unsigned short*)(wsb + 6*MB);
  unsigned short* vA = (unsigned short*)(wsb + 8*MB);
  unsigned short* qB = (unsigned short*)(wsb + 10*MB);
  unsigned short* kB = (unsigned short*)(wsb + 12*MB);
  unsigned short* vB = (unsigned short*)(wsb + 14*MB);
  short* wqT = (short*)(wsb + 16*MB);
  short* wkT = (short*)(wsb + 16*MB + 32*1024);
  short* wvT = (short*)(wsb + 16*MB + 64*1024);
  short* woT = (short*)(wsb + 16*MB + 96*1024);
  short* w1T = (short*)(wsb + 16*MB + 128*1024);           // 256 KB
  short* w2T = (short*)(wsb + 16*MB + 384*1024);           // 256 KB
  float* part = (float*)(wsb + 17*MB);                     // 64 KB

  wconv<<<dim3(80,4),256,0,stream>>>(wq,wk,wv,wo,w1,w2, wqT,wkT,wvT,woT,w1T,w2T);

  // head: embed + LN1(l0) + qkv(l0) -> A
  layer_kernel<true,false><<<256,1024,0,stream>>>(
      x, emb, nullptr, nullptr, nullptr,
      nullptr, nullptr, nullptr, nullptr,
      nullptr, nullptr, nullptr, nullptr,
      ln1s, ln1b,
      wqT, wkT, wvT, bq, bk, bv,
      qA, kA, vA, h, nullptr);

  for (int l = 0; l < 4; ++l) {
    unsigned short* qi = (l & 1) ? qB : qA;
    unsigned short* ki = (l & 1) ? kB : kA;
    unsigned short* vi = (l & 1) ? vB : vA;
    unsigned short* qu = (l & 1) ? qA : qB;
    unsigned short* ku = (l & 1) ? kA : kB;
    unsigned short* vu = (l & 1) ? vA : vB;
    if (l < 3) {
      layer_kernel<false,false><<<256,1024,0,stream>>>(
          nullptr, nullptr, qi, ki, vi,
          woT+4096*l, bo+64*l, ln2s+64*l, ln2b+64*l,
          w1T+32768*l, b1+512*l, w2T+32768*l, b2+64*l,
          ln1s+64*(l+1), ln1b+64*(l+1),
          wqT+4096*(l+1), wkT+4096*(l+1), wvT+4096*(l+1),
          bq+64*(l+1), bk+64*(l+1), bv+64*(l+1),
          qu, ku, vu, h, nullptr);
    } else {
      layer_kernel<false,true><<<256,1024,0,stream>>>(
          nullptr, nullptr, qi, ki, vi,
          woT+4096*l, bo+64*l, ln2s+64*l, ln2b+64*l,
          w1T+32768*l, b1+512*l, w2T+32768*l, b2+64*l,
          lnfs, lnfb,
          nullptr, nullptr, nullptr, nullptr, nullptr, nullptr,
          nullptr, nullptr, nullptr, h, part);
    }
  }
  pool_finalize<<<1,256,0,stream>>>(part, wcls, bcls, out);
}

// Round 22
// 165.070 us; speedup vs baseline: 1.2532x; 1.0119x over previous
//
#include <hip/hip_runtime.h>
#include <hip/hip_bf16.h>

#define DEV __device__ __forceinline__

typedef __attribute__((ext_vector_type(8))) short bf16x8;
typedef __attribute__((ext_vector_type(4))) float f32x4;
typedef __attribute__((ext_vector_type(16))) float f32x16;

// ---------- helpers ----------
DEV short f2bf(float x){ __hip_bfloat16 h = __float2bfloat16(x); return *(short*)&h; }
DEV unsigned pack2bf(float a, float b){
  return (unsigned)(unsigned short)f2bf(a) | ((unsigned)(unsigned short)f2bf(b) << 16);
}
DEV float fexp2(float x){ return __builtin_amdgcn_exp2f(x); }   // v_exp_f32
// gelu(x) = x * sigmoid(2z), z = 0.79788456(x + 0.044715x^3); exp folded to exp2, div -> rcp
DEV float gelu_fast(float x){
  float u = x + 0.044715f*x*x*x;
  float t = fexp2(-2.3022082f*u);
  return x * __builtin_amdgcn_rcpf(1.f + t);
}

#define SB 4096
#define NT 16384
#define DM 64
#define VST 586   // Vs row stride (ushorts); 293 dwords == 5 mod 32 -> writes 2-way, reads conflict-free

// ---------- weight convert+transpose: f32 [K][N] -> bf16 [N][K], 32x32 tiles ----------
__global__ __launch_bounds__(256) void wconv(
    const float* __restrict__ wq, const float* __restrict__ wk,
    const float* __restrict__ wv, const float* __restrict__ wo,
    const float* __restrict__ w1, const float* __restrict__ w2,
    short* __restrict__ wqT, short* __restrict__ wkT,
    short* __restrict__ wvT, short* __restrict__ woT,
    short* __restrict__ w1T, short* __restrict__ w2T)
{
  int t = blockIdx.x, l = blockIdx.y;
  const float* src; short* dst; int K, N, kt, nt;
  if (t < 16) {
    int m = t >> 2, sub = t & 3; kt = sub >> 1; nt = sub & 1; K = 64; N = 64;
    const float* s4[4] = {wq, wk, wv, wo};
    short*       d4[4] = {wqT, wkT, wvT, woT};
    src = s4[m] + l*4096; dst = d4[m] + l*4096;
  } else if (t < 48) {
    kt = (t-16) >> 4; nt = (t-16) & 15; K = 64; N = 512;
    src = w1 + l*32768; dst = w1T + l*32768;
  } else {
    kt = (t-48) >> 1; nt = (t-48) & 1; K = 512; N = 64;
    src = w2 + l*32768; dst = w2T + l*32768;
  }
  __shared__ float lds[32][33];
  int tx = threadIdx.x & 31, ty = threadIdx.x >> 5;
  int k0 = kt*32, n0 = nt*32;
  #pragma unroll
  for (int j=0;j<4;++j) lds[ty+8*j][tx] = src[(size_t)(k0+ty+8*j)*N + n0 + tx];
  __syncthreads();
  #pragma unroll
  for (int j=0;j<4;++j) {
    int nn = ty+8*j;
    dst[(size_t)(n0+nn)*K + k0 + tx] = f2bf(lds[tx][nn]);
  }
}

// ---------- merged layer kernel v4: 1024 threads (16 waves), 64 rows/block ----------
// K fragments read DIRECT from global (L2-resident, already fragment-layout);
// V staged transposed in LDS. LN'd activations materialized once into hB.
template<bool EMBED, bool LAST>
__global__ __launch_bounds__(1024,1) void layer_kernel(
    const int* __restrict__ x, const float* __restrict__ emb,
    const unsigned short* __restrict__ qin, const unsigned short* __restrict__ kin,
    const unsigned short* __restrict__ vin,
    const short* __restrict__ woT, const float* __restrict__ bo,
    const float* __restrict__ ln2s, const float* __restrict__ ln2b,
    const short* __restrict__ w1T, const float* __restrict__ b1,
    const short* __restrict__ w2T, const float* __restrict__ b2,
    const float* __restrict__ lns, const float* __restrict__ lnb,   // LN1(next) or LNf
    const short* __restrict__ wqT, const short* __restrict__ wkT, const short* __restrict__ wvT,
    const float* __restrict__ bq, const float* __restrict__ bk, const float* __restrict__ bv,
    unsigned short* __restrict__ qo, unsigned short* __restrict__ ko, unsigned short* __restrict__ vo,
    float* __restrict__ h, float* __restrict__ part)
{
  __shared__ uint4 regA4[4608];   // 73728 B: abL + hN + facc + hB
  __shared__ uint4 regB4[4688];   // 75008 B: Vs | mid
  __shared__ float mu[64], iv[64];

  unsigned short* abL = (unsigned short*)regA4;              // [64][72] bf16 (post-attn)
  float (*hN)[68]   = (float(*)[68])((char*)regA4 + 9216);
  float (*facc)[68] = (float(*)[68])((char*)regA4 + 26624);
  unsigned short* hB = (unsigned short*)((char*)regA4 + 44032);  // [64][72] bf16 LN'd
  unsigned short* Vs = (unsigned short*)regB4;               // [64][VST] transposed
  short (*mid)[520]  = (short(*)[520])regB4;

  const int bid = blockIdx.x;
  const int row_g0 = bid * 64;
  const int tid = threadIdx.x;
  const int w = tid >> 6, lane = tid & 63;     // w = 0..15
  const int r = lane & 15, kq = lane >> 4;
  const int srow = tid >> 4, sd4 = tid & 15;   // stats/embed: 16 lanes/row, 4 elems each

  if constexpr (EMBED) {
    int tg = row_g0 + srow;
    int s = tg & (SB-1);
    int tok = x[tg];
    #pragma unroll
    for (int i=0;i<4;++i) {
      int d = sd4*4 + i;
      float fe = (float)(d & ~1) * (1.0f/64.0f);
      float invk = __expf(-9.210340371976184f * fe);
      float ang = (float)s * invk;
      float pe = (d & 1) ? __cosf(ang) : __sinf(ang);
      float val = emb[tok*DM + d] + pe;
      hN[srow][d] = val;
      h[(size_t)tg*DM + d] = val;
    }
  } else {
    const int bbase = row_g0 & ~(SB-1);     // batch base token index
    const int kwin0 = row_g0 - 256;         // global token index of staged key 0

    // ---- stage V^T [64][VST] only; grp-major = coalesced global reads ----
    for (int idx = tid; idx < 4608; idx += 1024) {
      int e = idx >> 3, grp = idx & 7;
      int g = kwin0 + e;
      uint4 vv = make_uint4(0,0,0,0);
      if ((unsigned)(g - bbase) < (unsigned)SB)
        vv = *(const uint4*)(vin + (size_t)g*DM + grp*8);
      const unsigned short* pv = (const unsigned short*)&vv;
      #pragma unroll
      for (int d = 0; d < 8; ++d) Vs[(grp*8 + d)*VST + e] = pv[d];
    }
    __syncthreads();

    // ---- attention: wave w -> head hh = w>>1, q-subtile qs = w&1 (one job/wave) ----
    const int qc = lane & 31;
    const int hf = lane >> 5;
    const int hh = w >> 1, qs = w & 1;

    f32x16 oacc = {};
    float lacc = 0.f;
    {
      const int qglob = row_g0 + qs*32 + qc;
      bf16x8 qfrag = {};
      if (hf == 0) qfrag = *(const bf16x8*)(qin + (size_t)qglob*DM + hh*8);
      for (int t = 0; t <= 16; ++t) {
        const int k0l = qs*32 + 32*t;
        const int k0g = kwin0 + k0l;
        if (k0g > bbase + SB-1 || k0g + 31 < bbase) continue;

        bf16x8 kfrag = {};
        if (hf == 0) {
          int g = k0g + qc;
          int gc = g < bbase ? bbase : (g > bbase + SB-1 ? bbase + SB-1 : g);  // clamp; OOB rows masked below
          kfrag = *(const bf16x8*)(kin + (size_t)gc*DM + hh*8);
        }
        f32x16 s = __builtin_amdgcn_mfma_f32_32x32x16_bf16(kfrag, qfrag, (f32x16){}, 0, 0, 0);

        float pp[16];
        bool needmask = (t == 0) | (t == 16) | (k0g < bbase) | (k0g + 31 > bbase + SB-1);
        if (needmask) {
          #pragma unroll
          for (int rr = 0; rr < 16; ++rr) {
            int klg = k0g + (rr&3) + 8*(rr>>2) + 4*hf;
            bool ok = ((unsigned)(klg - qglob + 256) <= 512u) &&
                      ((unsigned)(klg - bbase) < (unsigned)SB);
            pp[rr] = ok ? fexp2(s[rr]) : 0.f;
          }
        } else {
          #pragma unroll
          for (int rr = 0; rr < 16; ++rr) pp[rr] = fexp2(s[rr]);
        }
        #pragma unroll
        for (int rr = 0; rr < 16; ++rr) lacc += pp[rr];

        unsigned pk[8];
        #pragma unroll
        for (int j = 0; j < 8; ++j) pk[j] = pack2bf(pp[2*j], pp[2*j+1]);
        unsigned sw[8];
        #pragma unroll
        for (int j = 0; j < 8; ++j) sw[j] = __shfl_xor(pk[j], 32, 64);

        union { unsigned u[4]; bf16x8 v; } pbA;
        pbA.u[0] = hf ? sw[2] : pk[0];
        pbA.u[1] = hf ? sw[3] : pk[1];
        pbA.u[2] = hf ? pk[2] : sw[0];
        pbA.u[3] = hf ? pk[3] : sw[1];
        bf16x8 va1 = {};
        if (qc < 8) va1 = *(const bf16x8*)(Vs + (hh*8 + qc)*VST + k0l + 8*hf);
        oacc = __builtin_amdgcn_mfma_f32_32x32x16_bf16(va1, pbA.v, oacc, 0, 0, 0);

        union { unsigned u[4]; bf16x8 v; } pbB;
        pbB.u[0] = hf ? sw[6] : pk[4];
        pbB.u[1] = hf ? sw[7] : pk[5];
        pbB.u[2] = hf ? pk[6] : sw[4];
        pbB.u[3] = hf ? pk[7] : sw[5];
        bf16x8 va2 = {};
        if (qc < 8) va2 = *(const bf16x8*)(Vs + (hh*8 + qc)*VST + k0l + 16 + 8*hf);
        oacc = __builtin_amdgcn_mfma_f32_32x32x16_bf16(va2, pbB.v, oacc, 0, 0, 0);
      }
    }
    float rcp = 1.f / (lacc + __shfl_xor(lacc, 32, 64));
    __syncthreads();    // all Vs reads complete

    // write attention output bf16 into abL
    {
      unsigned short ov[4];
      #pragma unroll
      for (int j = 0; j < 4; ++j) ov[j] = (unsigned short)f2bf(oacc[j] * rcp);
      *(uint2*)(abL + (qs*32 + qc)*72 + hh*8 + 4*hf) = *(uint2*)ov;
    }
    __syncthreads();

    // ---- attn-out projection + residual: wave (rh = w>>2, ct = w&3): 16 rows x 16 cols ----
    {
      const int rh = w >> 2, ct = w & 3;
      const int col = ct*16 + r;
      const short* wp = woT + (size_t)col*64 + kq*8;
      bf16x8 wb0 = *(const bf16x8*)(wp);
      bf16x8 wb1 = *(const bf16x8*)(wp + 32);
      const short* abp = (const short*)(abL + (rh*16 + r)*72 + kq*8);
      bf16x8 a0 = *(const bf16x8*)abp;
      bf16x8 a1 = *(const bf16x8*)(abp + 32);
      f32x4 acc = (f32x4){0.f,0.f,0.f,0.f};
      acc = __builtin_amdgcn_mfma_f32_16x16x32_bf16(a0, wb0, acc, 0, 0, 0);
      acc = __builtin_amdgcn_mfma_f32_16x16x32_bf16(a1, wb1, acc, 0, 0, 0);
      #pragma unroll
      for (int j=0;j<4;++j) {
        int rl = rh*16 + kq*4 + j;
        hN[rl][col] = acc[j] + bo[col] + h[(size_t)(row_g0+rl)*DM + col];
      }
    }
  }
  __syncthreads();

  // LN stats (LN1 for EMBED, LN2 otherwise): 16 lanes/row
  {
    const float* p = &hN[srow][sd4*4];
    float v0=p[0], v1=p[1], v2=p[2], v3=p[3];
    float sum = v0+v1+v2+v3;
    sum += __shfl_xor(sum, 1, 64); sum += __shfl_xor(sum, 2, 64);
    sum += __shfl_xor(sum, 4, 64); sum += __shfl_xor(sum, 8, 64);
    float mean = sum * (1.f/64.f);
    float d0=v0-mean, d1=v1-mean, d2=v2-mean, d3=v3-mean;
    float sq = d0*d0+d1*d1+d2*d2+d3*d3;
    sq += __shfl_xor(sq, 1, 64); sq += __shfl_xor(sq, 2, 64);
    sq += __shfl_xor(sq, 4, 64); sq += __shfl_xor(sq, 8, 64);
    if (sd4 == 0) { mu[srow] = mean; iv[srow] = rsqrtf(sq*(1.f/64.f) + 1e-6f); }
  }
  __syncthreads();

  // LN apply -> hB bf16 (ONCE; consumed as MFMA A-frags by fc1 / qkv)
  {
    const float* sS; const float* sBv;
    if constexpr (EMBED) { sS = lns; sBv = lnb; } else { sS = ln2s; sBv = ln2b; }
    float mean = mu[srow], inv = iv[srow];
    #pragma unroll
    for (int i=0;i<4;++i) {
      int d = sd4*4 + i;
      hB[srow*72 + d] = (unsigned short)f2bf((hN[srow][d]-mean)*inv*sS[d] + sBv[d]);
    }
  }
  __syncthreads();

  if constexpr (!EMBED) {
    // ---- fc1: wave w -> cols [32w, 32w+32), all 64 rows; A-frags from hB ----
    {
      bf16x8 a[4][2];
      #pragma unroll
      for (int rf=0; rf<4; ++rf) {
        const unsigned short* hp = hB + (rf*16 + r)*72 + kq*8;
        a[rf][0] = *(const bf16x8*)(hp);
        a[rf][1] = *(const bf16x8*)(hp + 32);
      }
      const int gc0 = w*32;
      bf16x8 wb[2][2];
      #pragma unroll
      for (int ct=0; ct<2; ++ct) {
        const short* wp = w1T + (size_t)(gc0 + ct*16 + r)*64 + kq*8;
        wb[ct][0] = *(const bf16x8*)(wp);
        wb[ct][1] = *(const bf16x8*)(wp + 32);
      }
      f32x4 acc1[2][4];
      #pragma unroll
      for (int ct=0;ct<2;++ct)
        #pragma unroll
        for (int rf=0;rf<4;++rf) acc1[ct][rf] = (f32x4){0.f,0.f,0.f,0.f};
      #pragma unroll
      for (int ct=0; ct<2; ++ct)
        #pragma unroll
        for (int rf=0; rf<4; ++rf) {
          acc1[ct][rf] = __builtin_amdgcn_mfma_f32_16x16x32_bf16(a[rf][0], wb[ct][0], acc1[ct][rf], 0, 0, 0);
          acc1[ct][rf] = __builtin_amdgcn_mfma_f32_16x16x32_bf16(a[rf][1], wb[ct][1], acc1[ct][rf], 0, 0, 0);
        }
      __syncthreads();   // Vs region free before mid writes
      #pragma unroll
      for (int ct=0; ct<2; ++ct) {
        int gcol = gc0 + ct*16 + r;
        float bb = b1[gcol];
        #pragma unroll
        for (int rf=0; rf<4; ++rf)
          #pragma unroll
          for (int j=0; j<4; ++j)
            mid[rf*16 + kq*4 + j][gcol] = f2bf(gelu_fast(acc1[ct][rf][j] + bb));
      }
    }
    __syncthreads();

    // ---- fc2: wave (kh = w>>3, rh2 = (w>>2)&1, ct2 = w&3): 32 rows x 16 cols, K-half ----
    {
      const int kh = w >> 3, rh2 = (w >> 2) & 1, ct2 = w & 3;
      const int col2 = ct2*16 + r;
      const int rbase = rh2*32;
      bf16x8 wf[8];
      #pragma unroll
      for (int ks=0; ks<8; ++ks)
        wf[ks] = *(const bf16x8*)(w2T + (size_t)col2*512 + kh*256 + ks*32 + kq*8);
      f32x4 acc2[2];
      #pragma unroll
      for (int rf=0;rf<2;++rf) acc2[rf] = (f32x4){0.f,0.f,0.f,0.f};
      #pragma unroll
      for (int ks=0; ks<8; ++ks)
        #pragma unroll
        for (int rf=0; rf<2; ++rf) {
          bf16x8 af = *(const bf16x8*)(&mid[rbase + rf*16 + r][kh*256 + ks*32 + kq*8]);
          acc2[rf] = __builtin_amdgcn_mfma_f32_16x16x32_bf16(af, wf[ks], acc2[rf], 0, 0, 0);
        }
      if (kh == 0) {
        #pragma unroll
        for (int rf=0; rf<2; ++rf)
          #pragma unroll
          for (int j=0;j<4;++j)
            facc[rbase + rf*16 + kq*4 + j][col2] = acc2[rf][j];
      }
      __syncthreads();
      if (kh == 1) {
        float bb = b2[col2];
        #pragma unroll
        for (int rf=0; rf<2; ++rf)
          #pragma unroll
          for (int j=0;j<4;++j) {
            int rl = rbase + rf*16 + kq*4 + j;
            float val = acc2[rf][j] + facc[rl][col2] + bb + hN[rl][col2];
            hN[rl][col2] = val;
            h[(size_t)(row_g0+rl)*DM + col2] = val;
          }
      }
    }
    __syncthreads();

    // LN stats for LN1(next) / LNf
    {
      const float* p = &hN[srow][sd4*4];
      float v0=p[0], v1=p[1], v2=p[2], v3=p[3];
      float sum = v0+v1+v2+v3;
      sum += __shfl_xor(sum, 1, 64); sum += __shfl_xor(sum, 2, 64);
      sum += __shfl_xor(sum, 4, 64); sum += __shfl_xor(sum, 8, 64);
      float mean = sum * (1.f/64.f);
      float d0=v0-mean, d1=v1-mean, d2=v2-mean, d3=v3-mean;
      float sq = d0*d0+d1*d1+d2*d2+d3*d3;
      sq += __shfl_xor(sq, 1, 64); sq += __shfl_xor(sq, 2, 64);
      sq += __shfl_xor(sq, 4, 64); sq += __shfl_xor(sq, 8, 64);
      if (sd4 == 0) { mu[srow] = mean; iv[srow] = rsqrtf(sq*(1.f/64.f) + 1e-6f); }
    }
    __syncthreads();
  }

  if constexpr (!LAST) {
    if constexpr (!EMBED) {
      // LN1(next) apply -> hB (EMBED already wrote hB with lns/lnb)
      float mean = mu[srow], inv = iv[srow];
      #pragma unroll
      for (int i=0;i<4;++i) {
        int d = sd4*4 + i;
        hB[srow*72 + d] = (unsigned short)f2bf((hN[srow][d]-mean)*inv*lns[d] + lnb[d]);
      }
      __syncthreads();
    }
    // qkv of (next) layer: 12 jobs; wave w does job w (w<12); A-frags from hB
    // qscale folds 1/sqrt(8) * log2(e) so attention can use exp2 directly.
    const float qscale = 0.51006977f;
    if (w < 12) {
      bf16x8 a[4][2];
      #pragma unroll
      for (int rf=0; rf<4; ++rf) {
        const unsigned short* hp = hB + (rf*16 + r)*72 + kq*8;
        a[rf][0] = *(const bf16x8*)(hp);
        a[rf][1] = *(const bf16x8*)(hp + 32);
      }
      int m = w >> 2, ct = w & 3;
      const short* WT = m==0 ? wqT : (m==1 ? wkT : wvT);
      int col = ct*16 + r;
      const short* wp = WT + (size_t)col*64 + kq*8;
      bf16x8 wb0 = *(const bf16x8*)(wp);
      bf16x8 wb1 = *(const bf16x8*)(wp + 32);
      float bias = (m==0 ? bq : (m==1 ? bk : bv))[col];
      float scale = (m==0) ? qscale : 1.f;
      unsigned short* OPT = m==0 ? qo : (m==1 ? ko : vo);
      #pragma unroll
      for (int rf=0; rf<4; ++rf) {
        f32x4 acc = (f32x4){0.f,0.f,0.f,0.f};
        acc = __builtin_amdgcn_mfma_f32_16x16x32_bf16(a[rf][0], wb0, acc, 0, 0, 0);
        acc = __builtin_amdgcn_mfma_f32_16x16x32_bf16(a[rf][1], wb1, acc, 0, 0, 0);
        #pragma unroll
        for (int j=0;j<4;++j) {
          size_t oi = (size_t)(row_g0 + rf*16 + kq*4 + j)*DM + col;
          OPT[oi] = (unsigned short)f2bf((acc[j] + bias)*scale);
        }
      }
    }
  } else {
    // final LN in place + pool partial (64 rows)
    float mean = mu[srow], inv = iv[srow];
    #pragma unroll
    for (int i=0;i<4;++i) {
      int d = sd4*4 + i;
      hN[srow][d] = (hN[srow][d]-mean)*inv*lns[d] + lnb[d];
    }
    __syncthreads();
    if (tid < 64) {
      float s = 0.f;
      #pragma unroll 4
      for (int rr=0; rr<64; ++rr) s += hN[rr][tid];
      part[bid*64 + tid] = s;
    }
  }
}

// ---------- pool finalize + classifier ----------
__global__ __launch_bounds__(256) void pool_finalize(const float* __restrict__ part,
    const float* __restrict__ wcls, const float* __restrict__ bcls, float* __restrict__ out)
{
  int tid = threadIdx.x;
  int b = tid >> 6, d = tid & 63;
  float sum = 0.f;
  #pragma unroll 8
  for (int i = 0; i < 64; ++i) sum += part[(b*64 + i)*64 + d];
  __shared__ float pooled[4][64];
  pooled[b][d] = sum * (1.f/4096.f);
  __syncthreads();
  if (tid < 40) {
    int bb = tid / 10, c = tid % 10;
    float acc = bcls[c];
    #pragma unroll
    for (int dd = 0; dd < 64; ++dd) acc = fmaf(pooled[bb][dd], wcls[dd*10 + c], acc);
    out[tid] = acc;
  }
}

// ---------- launcher ----------
extern "C" void kernel_launch(void* const* d_in, const int* in_sizes, int n_in,
                              void* d_out, int out_size, void* d_ws, size_t ws_size,
                              hipStream_t stream)
{
  const int*   x    = (const int*)d_in[0];
  const float* emb  = (const float*)d_in[1];
  const float* wq   = (const float*)d_in[2];
  const float* bq   = (const float*)d_in[3];
  const float* wk   = (const float*)d_in[4];
  const float* bk   = (const float*)d_in[5];
  const float* wv   = (const float*)d_in[6];
  const float* bv   = (const float*)d_in[7];
  const float* wo   = (const float*)d_in[8];
  const float* bo   = (const float*)d_in[9];
  const float* ln1s = (const float*)d_in[10];
  const float* ln1b = (const float*)d_in[11];
  const float* ln2s = (const float*)d_in[12];
  const float* ln2b = (const float*)d_in[13];
  const float* w1   = (const float*)d_in[14];
  const float* b1   = (const float*)d_in[15];
  const float* w2   = (const float*)d_in[16];
  const float* b2   = (const float*)d_in[17];
  const float* lnfs = (const float*)d_in[18];
  const float* lnfb = (const float*)d_in[19];
  const float* wcls = (const float*)d_in[20];
  const float* bcls = (const float*)d_in[21];
  float* out = (float*)d_out;

  char* wsb = (char*)d_ws;
  const size_t MB = 1u << 20;
  float* h  = (float*)(wsb);                               // 4 MB f32 [16384][64]
  unsigned short* qA = (unsigned short*)(wsb + 4*MB);      // ping-pong qkv (2 MB each)
  unsigned short* kA = (unsigned short*)(wsb + 6*MB);
  unsigned short* vA = (unsigned short*)(wsb + 8*MB);
  unsigned short* qB = (unsigned short*)(wsb + 10*MB);
  unsigned short* kB = (unsigned short*)(wsb + 12*MB);
  unsigned short* vB = (unsigned short*)(wsb + 14*MB);
  short* wqT = (short*)(wsb + 16*MB);
  short* wkT = (short*)(wsb + 16*MB + 32*1024);
  short* wvT = (short*)(wsb + 16*MB + 64*1024);
  short* woT = (short*)(wsb + 16*MB + 96*1024);
  short* w1T = (short*)(wsb + 16*MB + 128*1024);           // 256 KB
  short* w2T = (short*)(wsb + 16*MB + 384*1024);           // 256 KB
  float* part = (float*)(wsb + 17*MB);                     // 64 KB

  wconv<<<dim3(80,4),256,0,stream>>>(wq,wk,wv,wo,w1,w2, wqT,wkT,wvT,woT,w1T,w2T);

  // head: embed + LN1(l0) + qkv(l0) -> A
  layer_kernel<true,false><<<256,1024,0,stream>>>(
      x, emb, nullptr, nullptr, nullptr,
      nullptr, nullptr, nullptr, nullptr,
      nullptr, nullptr, nullptr, nullptr,
      ln1s, ln1b,
      wqT, wkT, wvT, bq, bk, bv,
      qA, kA, vA, h, nullptr);

  for (int l = 0; l < 4; ++l) {
    unsigned short* qi = (l & 1) ? qB : qA;
    unsigned short* ki = (l & 1) ? kB : kA;
    unsigned short* vi = (l & 1) ? vB : vA;
    unsigned short* qu = (l & 1) ? qA : qB;
    unsigned short* ku = (l & 1) ? kA : kB;
    unsigned short* vu = (l & 1) ? vA : vB;
    if (l < 3) {
      layer_kernel<false,false><<<256,1024,0,stream>>>(
          nullptr, nullptr, qi, ki, vi,
          woT+4096*l, bo+64*l, ln2s+64*l, ln2b+64*l,
          w1T+32768*l, b1+512*l, w2T+32768*l, b2+64*l,
          ln1s+64*(l+1), ln1b+64*(l+1),
          wqT+4096*(l+1), wkT+4096*(l+1), wvT+4096*(l+1),
          bq+64*(l+1), bk+64*(l+1), bv+64*(l+1),
          qu, ku, vu, h, nullptr);
    } else {
      layer_kernel<false,true><<<256,1024,0,stream>>>(
          nullptr, nullptr, qi, ki, vi,
          woT+4096*l, bo+64*l, ln2s+64*l, ln2b+64*l,
          w1T+32768*l, b1+512*l, w2T+32768*l, b2+64*l,
          lnfs, lnfb,
          nullptr, nullptr, nullptr, nullptr, nullptr, nullptr,
          nullptr, nullptr, nullptr, h, part);
    }
  }
  pool_finalize<<<1,256,0,stream>>>(part, wcls, bcls, out);
}